// Round 1
// baseline (428.919 us; speedup 1.0000x reference)
//
#include <hip/hip_runtime.h>
#include <hip/hip_bf16.h>

typedef __attribute__((ext_vector_type(8))) short bf16x8;
typedef __attribute__((ext_vector_type(4))) float f32x4;

#define MFMA_BF16(a, b, c) __builtin_amdgcn_mfma_f32_16x16x32_bf16((a), (b), (c), 0, 0, 0)

#define E_DIM 384
#define T_SEQ 256
#define B_BATCH 128
#define H_HEADS 6
#define D_HEAD 64
#define NROWS (B_BATCH * T_SEQ)   // 32768
#define FF_DIM (4 * E_DIM)        // 1536

// ---------------------------------------------------------------------------
// Weight transpose + cast: W[K][N] f32 -> WT[N][K] bf16
// ---------------------------------------------------------------------------
__global__ void tcast_kernel(const float* __restrict__ W,
                             __hip_bfloat16* __restrict__ WT, int K, int N) {
    int idx = blockIdx.x * 256 + threadIdx.x;
    if (idx >= K * N) return;
    int k = idx / N;
    int n = idx - k * N;
    WT[(size_t)n * K + k] = __float2bfloat16(W[idx]);
}

// ---------------------------------------------------------------------------
// LayerNorm: x[rows][384] f32 -> out[rows][384] bf16.  One wave per row.
// ---------------------------------------------------------------------------
__global__ __launch_bounds__(256) void ln_kernel(const float* __restrict__ x,
                                                 const float* __restrict__ g,
                                                 const float* __restrict__ bta,
                                                 __hip_bfloat16* __restrict__ out) {
    int row = blockIdx.x * 4 + (threadIdx.x >> 6);
    int lane = threadIdx.x & 63;
    const float* xr = x + (size_t)row * E_DIM;
    float vals[6];
    float s = 0.f;
#pragma unroll
    for (int i = 0; i < 6; i++) {
        vals[i] = xr[lane + i * 64];
        s += vals[i];
    }
#pragma unroll
    for (int off = 1; off < 64; off <<= 1) s += __shfl_xor(s, off, 64);
    float mu = s * (1.f / E_DIM);
    float vv = 0.f;
#pragma unroll
    for (int i = 0; i < 6; i++) {
        float d = vals[i] - mu;
        vv += d * d;
    }
#pragma unroll
    for (int off = 1; off < 64; off <<= 1) vv += __shfl_xor(vv, off, 64);
    float rstd = rsqrtf(vv * (1.f / E_DIM) + 1e-5f);
#pragma unroll
    for (int i = 0; i < 6; i++) {
        int c = lane + i * 64;
        out[(size_t)row * E_DIM + c] =
            __float2bfloat16((vals[i] - mu) * rstd * g[c] + bta[c]);
    }
}

// ---------------------------------------------------------------------------
// GEMM: C[M][N] = A[M][K] @ BT[N][K]^T, bf16 inputs, f32 accum.
// Tile 128x64, BK=64, 4 waves (2x2), each wave 64x32 via 16x16x32 MFMA.
// EPI: 0 = store bf16; 1 = +bias +f32 residual, store f32; 2 = +bias, relu, bf16
// ---------------------------------------------------------------------------
template <int EPI>
__global__ __launch_bounds__(256) void gemm_bt_kernel(
    const __hip_bfloat16* __restrict__ A, const __hip_bfloat16* __restrict__ BT,
    const float* __restrict__ bias, const float* resid,
    __hip_bfloat16* __restrict__ outb, float* outf, int M, int N, int K) {
    __shared__ __hip_bfloat16 As[128][64 + 8];
    __shared__ __hip_bfloat16 Bs[64][64 + 8];
    const int t = threadIdx.x;
    const int m0 = blockIdx.y * 128;
    const int n0 = blockIdx.x * 64;
    const int w = t >> 6, lane = t & 63;
    const int wr = w >> 1, wc = w & 1;
    const int l16 = lane & 15, lhi = lane >> 4;

    f32x4 acc[4][2] = {};

    for (int k0 = 0; k0 < K; k0 += 64) {
#pragma unroll
        for (int i = 0; i < 4; i++) {  // A tile: 128 rows x 8 chunks of 8 bf16
            int idx = i * 256 + t;
            int r = idx >> 3, c = (idx & 7) * 8;
            *reinterpret_cast<uint4*>(&As[r][c]) =
                *reinterpret_cast<const uint4*>(A + (size_t)(m0 + r) * K + k0 + c);
        }
#pragma unroll
        for (int i = 0; i < 2; i++) {  // B tile: 64 rows x 8 chunks
            int idx = i * 256 + t;
            int r = idx >> 3, c = (idx & 7) * 8;
            *reinterpret_cast<uint4*>(&Bs[r][c]) =
                *reinterpret_cast<const uint4*>(BT + (size_t)(n0 + r) * K + k0 + c);
        }
        __syncthreads();
#pragma unroll
        for (int kk = 0; kk < 2; kk++) {
            bf16x8 af[4], bf[2];
#pragma unroll
            for (int mr = 0; mr < 4; mr++)
                af[mr] = *reinterpret_cast<const bf16x8*>(
                    &As[wr * 64 + mr * 16 + l16][kk * 32 + lhi * 8]);
#pragma unroll
            for (int nr = 0; nr < 2; nr++)
                bf[nr] = *reinterpret_cast<const bf16x8*>(
                    &Bs[wc * 32 + nr * 16 + l16][kk * 32 + lhi * 8]);
#pragma unroll
            for (int mr = 0; mr < 4; mr++)
#pragma unroll
                for (int nr = 0; nr < 2; nr++)
                    acc[mr][nr] = MFMA_BF16(af[mr], bf[nr], acc[mr][nr]);
        }
        __syncthreads();
    }

#pragma unroll
    for (int mr = 0; mr < 4; mr++) {
#pragma unroll
        for (int nr = 0; nr < 2; nr++) {
            int col = n0 + wc * 32 + nr * 16 + l16;
#pragma unroll
            for (int r = 0; r < 4; r++) {
                int row = m0 + wr * 64 + mr * 16 + lhi * 4 + r;
                size_t off = (size_t)row * N + col;
                float v = acc[mr][nr][r];
                if (EPI == 0) {
                    outb[off] = __float2bfloat16(v);
                } else if (EPI == 1) {
                    outf[off] = v + bias[col] + resid[off];
                } else {
                    v += bias[col];
                    outb[off] = __float2bfloat16(v > 0.f ? v : 0.f);
                }
            }
        }
    }
}

// ---------------------------------------------------------------------------
// Causal attention, one block per (b,h). 4 waves; wave w owns Q rows
// [64w, 64w+64). K staged in LDS, V staged transposed, Q in registers.
// Online softmax over KV tiles of 64. scale = 384^-0.5 (reference uses C).
// ---------------------------------------------------------------------------
__global__ __launch_bounds__(256, 1) void attn_kernel(
    const __hip_bfloat16* __restrict__ q, const __hip_bfloat16* __restrict__ k,
    const __hip_bfloat16* __restrict__ v, __hip_bfloat16* __restrict__ o) {
    __shared__ __hip_bfloat16 Ks[T_SEQ][72];
    __shared__ __hip_bfloat16 VTs[D_HEAD][272];
    __shared__ __hip_bfloat16 Ps[4][64][72];

    const int bh = blockIdx.x;
    const int b = bh / H_HEADS, h = bh - b * H_HEADS;
    const int t = threadIdx.x;
    const int w = t >> 6, lane = t & 63;
    const int l16 = lane & 15, lhi = lane >> 4;
    const size_t base = ((size_t)b * T_SEQ) * E_DIM + h * D_HEAD;
    const float scale = 0.051031036307982884f;  // 384^-0.5

    // stage K rows (256 x 64)
#pragma unroll
    for (int i = 0; i < 8; i++) {
        int idx = i * 256 + t;
        int r = idx >> 3, c = (idx & 7) * 8;
        *reinterpret_cast<uint4*>(&Ks[r][c]) =
            *reinterpret_cast<const uint4*>(k + base + (size_t)r * E_DIM + c);
    }
    // stage V transposed: VTs[d][t]
#pragma unroll
    for (int i = 0; i < 8; i++) {
        int idx = i * 256 + t;
        int r = idx >> 3, d0 = (idx & 7) * 8;
        uint4 val = *reinterpret_cast<const uint4*>(v + base + (size_t)r * E_DIM + d0);
        const __hip_bfloat16* p8 = reinterpret_cast<const __hip_bfloat16*>(&val);
#pragma unroll
        for (int j = 0; j < 8; j++) VTs[d0 + j][r] = p8[j];
    }
    __syncthreads();

    // Q fragments in registers: rows 64w..64w+63
    bf16x8 qf[4][2];
#pragma unroll
    for (int mr = 0; mr < 4; mr++)
#pragma unroll
        for (int kk = 0; kk < 2; kk++)
            qf[mr][kk] = *reinterpret_cast<const bf16x8*>(
                q + base + (size_t)(w * 64 + mr * 16 + l16) * E_DIM + kk * 32 + lhi * 8);

    float mstate[4][4], lstate[4][4];
    f32x4 oacc[4][4] = {};
#pragma unroll
    for (int mr = 0; mr < 4; mr++)
#pragma unroll
        for (int r = 0; r < 4; r++) {
            mstate[mr][r] = -INFINITY;
            lstate[mr][r] = 0.f;
        }

    for (int jt = 0; jt <= w; jt++) {
        // S = Q @ K_tile^T
        f32x4 s[4][4] = {};
#pragma unroll
        for (int kk = 0; kk < 2; kk++) {
            bf16x8 kf[4];
#pragma unroll
            for (int nr = 0; nr < 4; nr++)
                kf[nr] = *reinterpret_cast<const bf16x8*>(
                    &Ks[jt * 64 + nr * 16 + l16][kk * 32 + lhi * 8]);
#pragma unroll
            for (int mr = 0; mr < 4; mr++)
#pragma unroll
                for (int nr = 0; nr < 4; nr++)
                    s[mr][nr] = MFMA_BF16(qf[mr][kk], kf[nr], s[mr][nr]);
        }
        // mask + online softmax per row
#pragma unroll
        for (int mr = 0; mr < 4; mr++) {
#pragma unroll
            for (int r = 0; r < 4; r++) {
                int qrow = w * 64 + mr * 16 + lhi * 4 + r;
                float pv[4];
                float mx = -INFINITY;
#pragma unroll
                for (int nr = 0; nr < 4; nr++) {
                    int kcol = jt * 64 + nr * 16 + l16;
                    float val = s[mr][nr][r] * scale;
                    if (kcol > qrow) val = -1e30f;
                    pv[nr] = val;
                    mx = fmaxf(mx, val);
                }
#pragma unroll
                for (int off = 1; off < 16; off <<= 1)
                    mx = fmaxf(mx, __shfl_xor(mx, off, 64));
                float mold = mstate[mr][r];
                float mnew = fmaxf(mold, mx);
                float corr = __expf(mold - mnew);
                float psum = 0.f;
#pragma unroll
                for (int nr = 0; nr < 4; nr++) {
                    float p = __expf(pv[nr] - mnew);
                    pv[nr] = p;
                    psum += p;
                }
#pragma unroll
                for (int off = 1; off < 16; off <<= 1)
                    psum += __shfl_xor(psum, off, 64);
                lstate[mr][r] = lstate[mr][r] * corr + psum;
                mstate[mr][r] = mnew;
#pragma unroll
                for (int dr = 0; dr < 4; dr++) oacc[mr][dr][r] *= corr;
#pragma unroll
                for (int nr = 0; nr < 4; nr++)
                    Ps[w][mr * 16 + lhi * 4 + r][nr * 16 + l16] = __float2bfloat16(pv[nr]);
            }
        }
        // O += P @ V_tile   (A = P from LDS, B = V^T rows)
#pragma unroll
        for (int kk = 0; kk < 2; kk++) {
            bf16x8 pa[4], vb[4];
#pragma unroll
            for (int mr = 0; mr < 4; mr++)
                pa[mr] = *reinterpret_cast<const bf16x8*>(
                    &Ps[w][mr * 16 + l16][kk * 32 + lhi * 8]);
#pragma unroll
            for (int dr = 0; dr < 4; dr++)
                vb[dr] = *reinterpret_cast<const bf16x8*>(
                    &VTs[dr * 16 + l16][jt * 64 + kk * 32 + lhi * 8]);
#pragma unroll
            for (int mr = 0; mr < 4; mr++)
#pragma unroll
                for (int dr = 0; dr < 4; dr++)
                    oacc[mr][dr] = MFMA_BF16(pa[mr], vb[dr], oacc[mr][dr]);
        }
    }

    // write O / l
#pragma unroll
    for (int mr = 0; mr < 4; mr++) {
#pragma unroll
        for (int r = 0; r < 4; r++) {
            float rl = 1.f / lstate[mr][r];
            int row = w * 64 + mr * 16 + lhi * 4 + r;
#pragma unroll
            for (int dr = 0; dr < 4; dr++)
                o[base + (size_t)row * E_DIM + dr * 16 + l16] =
                    __float2bfloat16(oacc[mr][dr][r] * rl);
        }
    }
}

// ---------------------------------------------------------------------------
extern "C" void kernel_launch(void* const* d_in, const int* in_sizes, int n_in,
                              void* d_out, int out_size, void* d_ws, size_t ws_size,
                              hipStream_t stream) {
    const float* x      = (const float*)d_in[0];
    const float* wq     = (const float*)d_in[1];
    const float* wk     = (const float*)d_in[2];
    const float* wv     = (const float*)d_in[3];
    const float* w_proj = (const float*)d_in[4];
    const float* b_proj = (const float*)d_in[5];
    const float* w1     = (const float*)d_in[6];
    const float* b1     = (const float*)d_in[7];
    const float* w2     = (const float*)d_in[8];
    const float* b2     = (const float*)d_in[9];
    const float* g1     = (const float*)d_in[10];
    const float* bt1    = (const float*)d_in[11];
    const float* g2     = (const float*)d_in[12];
    const float* bt2    = (const float*)d_in[13];
    float* out = (float*)d_out;

    char* ws = (char*)d_ws;
    size_t off = 0;
    auto alloc = [&](size_t bytes) {
        void* p = ws + off;
        off += (bytes + 255) & ~(size_t)255;
        return p;
    };
    const size_t wElems = E_DIM * E_DIM;         // 147456
    const size_t fElems = E_DIM * FF_DIM;        // 589824
    const size_t actElems = (size_t)NROWS * E_DIM;
    __hip_bfloat16* wqT = (__hip_bfloat16*)alloc(wElems * 2);
    __hip_bfloat16* wkT = (__hip_bfloat16*)alloc(wElems * 2);
    __hip_bfloat16* wvT = (__hip_bfloat16*)alloc(wElems * 2);
    __hip_bfloat16* wpT = (__hip_bfloat16*)alloc(wElems * 2);
    __hip_bfloat16* w1T = (__hip_bfloat16*)alloc(fElems * 2);
    __hip_bfloat16* w2T = (__hip_bfloat16*)alloc(fElems * 2);
    __hip_bfloat16* lnb = (__hip_bfloat16*)alloc(actElems * 2);  // ln1, later ln2
    __hip_bfloat16* qb  = (__hip_bfloat16*)alloc(actElems * 2);
    __hip_bfloat16* kb  = (__hip_bfloat16*)alloc(actElems * 2);
    __hip_bfloat16* vb  = (__hip_bfloat16*)alloc(actElems * 2);
    __hip_bfloat16* ab  = (__hip_bfloat16*)alloc(actElems * 2);  // attn out
    __hip_bfloat16* h1  = qb;   // FFN hidden reuses q|k|v|attn (contiguous)
    float* x2 = out;            // residual stream lives in d_out

    // 1) weights -> bf16 transposed
    tcast_kernel<<<(wElems + 255) / 256, 256, 0, stream>>>(wq, wqT, E_DIM, E_DIM);
    tcast_kernel<<<(wElems + 255) / 256, 256, 0, stream>>>(wk, wkT, E_DIM, E_DIM);
    tcast_kernel<<<(wElems + 255) / 256, 256, 0, stream>>>(wv, wvT, E_DIM, E_DIM);
    tcast_kernel<<<(wElems + 255) / 256, 256, 0, stream>>>(w_proj, wpT, E_DIM, E_DIM);
    tcast_kernel<<<(fElems + 255) / 256, 256, 0, stream>>>(w1, w1T, E_DIM, FF_DIM);
    tcast_kernel<<<(fElems + 255) / 256, 256, 0, stream>>>(w2, w2T, FF_DIM, E_DIM);

    // 2) ln1
    ln_kernel<<<NROWS / 4, 256, 0, stream>>>(x, g1, bt1, lnb);

    // 3) q,k,v
    dim3 gQKV(E_DIM / 64, NROWS / 128);
    gemm_bt_kernel<0><<<gQKV, 256, 0, stream>>>(lnb, wqT, nullptr, nullptr, qb, nullptr, NROWS, E_DIM, E_DIM);
    gemm_bt_kernel<0><<<gQKV, 256, 0, stream>>>(lnb, wkT, nullptr, nullptr, kb, nullptr, NROWS, E_DIM, E_DIM);
    gemm_bt_kernel<0><<<gQKV, 256, 0, stream>>>(lnb, wvT, nullptr, nullptr, vb, nullptr, NROWS, E_DIM, E_DIM);

    // 4) attention
    attn_kernel<<<B_BATCH * H_HEADS, 256, 0, stream>>>(qb, kb, vb, ab);

    // 5) x2 = x + attn @ w_proj + b_proj  (f32, in d_out)
    gemm_bt_kernel<1><<<gQKV, 256, 0, stream>>>(ab, wpT, b_proj, x, nullptr, x2, NROWS, E_DIM, E_DIM);

    // 6) ln2
    ln_kernel<<<NROWS / 4, 256, 0, stream>>>(x2, g2, bt2, lnb);

    // 7) h1 = relu(ln2 @ w1 + b1)
    dim3 gF1(FF_DIM / 64, NROWS / 128);
    gemm_bt_kernel<2><<<gF1, 256, 0, stream>>>(lnb, w1T, b1, nullptr, h1, nullptr, NROWS, FF_DIM, E_DIM);

    // 8) out = x2 + h1 @ w2 + b2
    gemm_bt_kernel<1><<<gQKV, 256, 0, stream>>>(h1, w2T, b2, x2, nullptr, out, NROWS, E_DIM, FF_DIM);
}

// Round 2
// 346.116 us; speedup vs baseline: 1.2392x; 1.2392x over previous
//
#include <hip/hip_runtime.h>
#include <hip/hip_bf16.h>

typedef __attribute__((ext_vector_type(8))) short bf16x8;
typedef __attribute__((ext_vector_type(4))) float f32x4;

#define MFMA_BF16(a, b, c) __builtin_amdgcn_mfma_f32_16x16x32_bf16((a), (b), (c), 0, 0, 0)

#define E_DIM 384
#define T_SEQ 256
#define B_BATCH 128
#define H_HEADS 6
#define D_HEAD 64
#define NROWS (B_BATCH * T_SEQ)   // 32768
#define FF_DIM (4 * E_DIM)        // 1536
#define QKV_LD 1152               // 3*E

__device__ __forceinline__ void load_lds16(const __hip_bfloat16* g, __hip_bfloat16* l) {
    __builtin_amdgcn_global_load_lds(
        (const __attribute__((address_space(1))) void*)g,
        (__attribute__((address_space(3))) void*)l, 16, 0, 0);
}

// ---------------------------------------------------------------------------
// Weight transpose + cast: W[K][N] f32 -> WT[N][K] bf16
// ---------------------------------------------------------------------------
__global__ void tcast_kernel(const float* __restrict__ W,
                             __hip_bfloat16* __restrict__ WT, int K, int N) {
    int idx = blockIdx.x * 256 + threadIdx.x;
    if (idx >= K * N) return;
    int k = idx / N;
    int n = idx - k * N;
    WT[(size_t)n * K + k] = __float2bfloat16(W[idx]);
}

// ---------------------------------------------------------------------------
// LayerNorm: x[rows][384] f32 -> out[rows][384] bf16.  One wave per row.
// ---------------------------------------------------------------------------
__global__ __launch_bounds__(256) void ln_kernel(const float* __restrict__ x,
                                                 const float* __restrict__ g,
                                                 const float* __restrict__ bta,
                                                 __hip_bfloat16* __restrict__ out) {
    int row = blockIdx.x * 4 + (threadIdx.x >> 6);
    int lane = threadIdx.x & 63;
    const float* xr = x + (size_t)row * E_DIM;
    float vals[6];
    float s = 0.f;
#pragma unroll
    for (int i = 0; i < 6; i++) {
        vals[i] = xr[lane + i * 64];
        s += vals[i];
    }
#pragma unroll
    for (int off = 1; off < 64; off <<= 1) s += __shfl_xor(s, off, 64);
    float mu = s * (1.f / E_DIM);
    float vv = 0.f;
#pragma unroll
    for (int i = 0; i < 6; i++) {
        float d = vals[i] - mu;
        vv += d * d;
    }
#pragma unroll
    for (int off = 1; off < 64; off <<= 1) vv += __shfl_xor(vv, off, 64);
    float rstd = rsqrtf(vv * (1.f / E_DIM) + 1e-5f);
#pragma unroll
    for (int i = 0; i < 6; i++) {
        int c = lane + i * 64;
        out[(size_t)row * E_DIM + c] =
            __float2bfloat16((vals[i] - mu) * rstd * g[c] + bta[c]);
    }
}

// ---------------------------------------------------------------------------
// GEMM (m97 structure): C[M][N] = A[M][K] @ BT[N][K]^T, bf16 in, f32 accum.
// Tile 128x128, BK=64, 4 waves (2x2), each wave 64x64 via 4x4 16x16x32 MFMA.
// Staging via global_load_lds width-16 into linear LDS.
// EPI: 0 = store bf16; 1 = +bias +f32 residual, store f32; 2 = +bias, relu, bf16
// ---------------------------------------------------------------------------
template <int EPI>
__global__ __launch_bounds__(256) void gemm128_kernel(
    const __hip_bfloat16* __restrict__ A, const __hip_bfloat16* __restrict__ BT,
    const float* __restrict__ bias, const float* __restrict__ resid,
    __hip_bfloat16* __restrict__ outb, float* __restrict__ outf,
    int M, int N, int K) {
    __shared__ __hip_bfloat16 As[128 * 64];
    __shared__ __hip_bfloat16 Bs[128 * 64];
    const int t = threadIdx.x;
    const int w = t >> 6, lane = t & 63;
    const int l16 = lane & 15, lhi = lane >> 4;
    const int wr = w >> 1, wc = w & 1;

    // XCD-aware chunked swizzle (grid divisible by 8 for all our shapes)
    const int nwg = gridDim.x;
    const int bid = blockIdx.x;
    const int cpx = nwg >> 3;
    const int swz = (bid & 7) * cpx + (bid >> 3);
    const int nb = N >> 7;
    const int m0 = (swz / nb) * 128;
    const int n0 = (swz % nb) * 128;

    f32x4 acc[4][4] = {};

    for (int k0 = 0; k0 < K; k0 += 64) {
#pragma unroll
        for (int i = 0; i < 4; i++) {
            int e = (i * 256 + t) * 8;     // flat bf16 elem in 128x64 tile
            int r = e >> 6, c = e & 63;
            load_lds16(A + (size_t)(m0 + r) * K + k0 + c, &As[e]);
            load_lds16(BT + (size_t)(n0 + r) * K + k0 + c, &Bs[e]);
        }
        __syncthreads();
#pragma unroll
        for (int kk = 0; kk < 2; kk++) {
            bf16x8 af[4], bfr[4];
#pragma unroll
            for (int mr = 0; mr < 4; mr++)
                af[mr] = *reinterpret_cast<const bf16x8*>(
                    &As[(wr * 64 + mr * 16 + l16) * 64 + kk * 32 + lhi * 8]);
#pragma unroll
            for (int nr = 0; nr < 4; nr++)
                bfr[nr] = *reinterpret_cast<const bf16x8*>(
                    &Bs[(wc * 64 + nr * 16 + l16) * 64 + kk * 32 + lhi * 8]);
#pragma unroll
            for (int mr = 0; mr < 4; mr++)
#pragma unroll
                for (int nr = 0; nr < 4; nr++)
                    acc[mr][nr] = MFMA_BF16(af[mr], bfr[nr], acc[mr][nr]);
        }
        __syncthreads();
    }

#pragma unroll
    for (int mr = 0; mr < 4; mr++) {
#pragma unroll
        for (int nr = 0; nr < 4; nr++) {
            int col = n0 + wc * 64 + nr * 16 + l16;
#pragma unroll
            for (int r = 0; r < 4; r++) {
                int row = m0 + wr * 64 + mr * 16 + lhi * 4 + r;
                size_t off = (size_t)row * N + col;
                float v = acc[mr][nr][r];
                if (EPI == 0) {
                    outb[off] = __float2bfloat16(v);
                } else if (EPI == 1) {
                    outf[off] = v + bias[col] + resid[off];
                } else {
                    v += bias[col];
                    outb[off] = __float2bfloat16(v > 0.f ? v : 0.f);
                }
            }
        }
    }
}

// ---------------------------------------------------------------------------
// Causal attention, one block per (b,h). qkv packed [rows][1152].
// ---------------------------------------------------------------------------
__global__ __launch_bounds__(256, 1) void attn_kernel(
    const __hip_bfloat16* __restrict__ qkv, __hip_bfloat16* __restrict__ o) {
    __shared__ __hip_bfloat16 Ks[T_SEQ][72];
    __shared__ __hip_bfloat16 VTs[D_HEAD][272];
    __shared__ __hip_bfloat16 Ps[4][64][72];

    const int bh = blockIdx.x;
    const int b = bh / H_HEADS, h = bh - b * H_HEADS;
    const int t = threadIdx.x;
    const int w = t >> 6, lane = t & 63;
    const int l16 = lane & 15, lhi = lane >> 4;
    const size_t rbase = (size_t)b * T_SEQ;
    const int qoff = h * D_HEAD, koff = E_DIM + h * D_HEAD, voff = 2 * E_DIM + h * D_HEAD;
    const float scale = 0.051031036307982884f;  // 384^-0.5

    // stage K rows (256 x 64)
#pragma unroll
    for (int i = 0; i < 8; i++) {
        int idx = i * 256 + t;
        int r = idx >> 3, c = (idx & 7) * 8;
        *reinterpret_cast<uint4*>(&Ks[r][c]) =
            *reinterpret_cast<const uint4*>(qkv + (rbase + r) * QKV_LD + koff + c);
    }
    // stage V transposed: VTs[d][t]
#pragma unroll
    for (int i = 0; i < 8; i++) {
        int idx = i * 256 + t;
        int r = idx >> 3, d0 = (idx & 7) * 8;
        uint4 val = *reinterpret_cast<const uint4*>(qkv + (rbase + r) * QKV_LD + voff + d0);
        const __hip_bfloat16* p8 = reinterpret_cast<const __hip_bfloat16*>(&val);
#pragma unroll
        for (int j = 0; j < 8; j++) VTs[d0 + j][r] = p8[j];
    }
    __syncthreads();

    // Q fragments in registers: rows 64w..64w+63
    bf16x8 qf[4][2];
#pragma unroll
    for (int mr = 0; mr < 4; mr++)
#pragma unroll
        for (int kk = 0; kk < 2; kk++)
            qf[mr][kk] = *reinterpret_cast<const bf16x8*>(
                qkv + (rbase + w * 64 + mr * 16 + l16) * QKV_LD + qoff + kk * 32 + lhi * 8);

    float mstate[4][4], lstate[4][4];
    f32x4 oacc[4][4] = {};
#pragma unroll
    for (int mr = 0; mr < 4; mr++)
#pragma unroll
        for (int r = 0; r < 4; r++) {
            mstate[mr][r] = -INFINITY;
            lstate[mr][r] = 0.f;
        }

    for (int jt = 0; jt <= w; jt++) {
        f32x4 s[4][4] = {};
#pragma unroll
        for (int kk = 0; kk < 2; kk++) {
            bf16x8 kf[4];
#pragma unroll
            for (int nr = 0; nr < 4; nr++)
                kf[nr] = *reinterpret_cast<const bf16x8*>(
                    &Ks[jt * 64 + nr * 16 + l16][kk * 32 + lhi * 8]);
#pragma unroll
            for (int mr = 0; mr < 4; mr++)
#pragma unroll
                for (int nr = 0; nr < 4; nr++)
                    s[mr][nr] = MFMA_BF16(qf[mr][kk], kf[nr], s[mr][nr]);
        }
#pragma unroll
        for (int mr = 0; mr < 4; mr++) {
#pragma unroll
            for (int r = 0; r < 4; r++) {
                int qrow = w * 64 + mr * 16 + lhi * 4 + r;
                float pv[4];
                float mx = -INFINITY;
#pragma unroll
                for (int nr = 0; nr < 4; nr++) {
                    int kcol = jt * 64 + nr * 16 + l16;
                    float val = s[mr][nr][r] * scale;
                    if (kcol > qrow) val = -1e30f;
                    pv[nr] = val;
                    mx = fmaxf(mx, val);
                }
#pragma unroll
                for (int off = 1; off < 16; off <<= 1)
                    mx = fmaxf(mx, __shfl_xor(mx, off, 64));
                float mold = mstate[mr][r];
                float mnew = fmaxf(mold, mx);
                float corr = __expf(mold - mnew);
                float psum = 0.f;
#pragma unroll
                for (int nr = 0; nr < 4; nr++) {
                    float p = __expf(pv[nr] - mnew);
                    pv[nr] = p;
                    psum += p;
                }
#pragma unroll
                for (int off = 1; off < 16; off <<= 1)
                    psum += __shfl_xor(psum, off, 64);
                lstate[mr][r] = lstate[mr][r] * corr + psum;
                mstate[mr][r] = mnew;
#pragma unroll
                for (int dr = 0; dr < 4; dr++) oacc[mr][dr][r] *= corr;
#pragma unroll
                for (int nr = 0; nr < 4; nr++)
                    Ps[w][mr * 16 + lhi * 4 + r][nr * 16 + l16] = __float2bfloat16(pv[nr]);
            }
        }
#pragma unroll
        for (int kk = 0; kk < 2; kk++) {
            bf16x8 pa[4], vbf[4];
#pragma unroll
            for (int mr = 0; mr < 4; mr++)
                pa[mr] = *reinterpret_cast<const bf16x8*>(
                    &Ps[w][mr * 16 + l16][kk * 32 + lhi * 8]);
#pragma unroll
            for (int dr = 0; dr < 4; dr++)
                vbf[dr] = *reinterpret_cast<const bf16x8*>(
                    &VTs[dr * 16 + l16][jt * 64 + kk * 32 + lhi * 8]);
#pragma unroll
            for (int mr = 0; mr < 4; mr++)
#pragma unroll
                for (int dr = 0; dr < 4; dr++)
                    oacc[mr][dr] = MFMA_BF16(pa[mr], vbf[dr], oacc[mr][dr]);
        }
    }

#pragma unroll
    for (int mr = 0; mr < 4; mr++) {
#pragma unroll
        for (int r = 0; r < 4; r++) {
            float rl = 1.f / lstate[mr][r];
            int row = w * 64 + mr * 16 + lhi * 4 + r;
#pragma unroll
            for (int dr = 0; dr < 4; dr++)
                o[(rbase + row) * E_DIM + h * D_HEAD + dr * 16 + l16] =
                    __float2bfloat16(oacc[mr][dr][r] * rl);
        }
    }
}

// ---------------------------------------------------------------------------
extern "C" void kernel_launch(void* const* d_in, const int* in_sizes, int n_in,
                              void* d_out, int out_size, void* d_ws, size_t ws_size,
                              hipStream_t stream) {
    const float* x      = (const float*)d_in[0];
    const float* wq     = (const float*)d_in[1];
    const float* wk     = (const float*)d_in[2];
    const float* wv     = (const float*)d_in[3];
    const float* w_proj = (const float*)d_in[4];
    const float* b_proj = (const float*)d_in[5];
    const float* w1     = (const float*)d_in[6];
    const float* b1     = (const float*)d_in[7];
    const float* w2     = (const float*)d_in[8];
    const float* b2     = (const float*)d_in[9];
    const float* g1     = (const float*)d_in[10];
    const float* bt1    = (const float*)d_in[11];
    const float* g2     = (const float*)d_in[12];
    const float* bt2    = (const float*)d_in[13];
    float* out = (float*)d_out;

    char* ws = (char*)d_ws;
    size_t off = 0;
    auto alloc = [&](size_t bytes) {
        void* p = ws + off;
        off += (bytes + 255) & ~(size_t)255;
        return p;
    };
    const size_t wElems = E_DIM * E_DIM;
    const size_t fElems = E_DIM * FF_DIM;
    const size_t actElems = (size_t)NROWS * E_DIM;
    __hip_bfloat16* wqkvT = (__hip_bfloat16*)alloc(3 * wElems * 2);  // [1152][384]
    __hip_bfloat16* wpT   = (__hip_bfloat16*)alloc(wElems * 2);
    __hip_bfloat16* w1T   = (__hip_bfloat16*)alloc(fElems * 2);
    __hip_bfloat16* w2T   = (__hip_bfloat16*)alloc(fElems * 2);
    __hip_bfloat16* lnb   = (__hip_bfloat16*)alloc(actElems * 2);      // ln1 / ln2
    __hip_bfloat16* qkv   = (__hip_bfloat16*)alloc(3 * actElems * 2);  // [32768][1152]
    __hip_bfloat16* ab    = (__hip_bfloat16*)alloc(actElems * 2);      // attn out
    __hip_bfloat16* h1    = qkv;  // FFN hidden (96MB) reuses qkv+ab (100MB contiguous)
    float* x2 = out;

    // 1) weights -> bf16 transposed (wq|wk|wv stacked rows)
    tcast_kernel<<<(wElems + 255) / 256, 256, 0, stream>>>(wq, wqkvT, E_DIM, E_DIM);
    tcast_kernel<<<(wElems + 255) / 256, 256, 0, stream>>>(wk, wqkvT + wElems, E_DIM, E_DIM);
    tcast_kernel<<<(wElems + 255) / 256, 256, 0, stream>>>(wv, wqkvT + 2 * wElems, E_DIM, E_DIM);
    tcast_kernel<<<(wElems + 255) / 256, 256, 0, stream>>>(w_proj, wpT, E_DIM, E_DIM);
    tcast_kernel<<<(fElems + 255) / 256, 256, 0, stream>>>(w1, w1T, E_DIM, FF_DIM);
    tcast_kernel<<<(fElems + 255) / 256, 256, 0, stream>>>(w2, w2T, FF_DIM, E_DIM);

    // 2) ln1
    ln_kernel<<<NROWS / 4, 256, 0, stream>>>(x, g1, bt1, lnb);

    // 3) fused qkv: [32768][1152]
    gemm128_kernel<0><<<(NROWS / 128) * (QKV_LD / 128), 256, 0, stream>>>(
        lnb, wqkvT, nullptr, nullptr, qkv, nullptr, NROWS, QKV_LD, E_DIM);

    // 4) attention
    attn_kernel<<<B_BATCH * H_HEADS, 256, 0, stream>>>(qkv, ab);

    // 5) x2 = x + attn @ w_proj + b_proj  (f32, in d_out)
    gemm128_kernel<1><<<(NROWS / 128) * (E_DIM / 128), 256, 0, stream>>>(
        ab, wpT, b_proj, x, nullptr, x2, NROWS, E_DIM, E_DIM);

    // 6) ln2
    ln_kernel<<<NROWS / 4, 256, 0, stream>>>(x2, g2, bt2, lnb);

    // 7) h1 = relu(ln2 @ w1 + b1)
    gemm128_kernel<2><<<(NROWS / 128) * (FF_DIM / 128), 256, 0, stream>>>(
        lnb, w1T, b1, nullptr, h1, nullptr, NROWS, FF_DIM, E_DIM);

    // 8) out = x2 + h1 @ w2 + b2
    gemm128_kernel<1><<<(NROWS / 128) * (E_DIM / 128), 256, 0, stream>>>(
        h1, w2T, b2, x2, nullptr, out, NROWS, E_DIM, FF_DIM);
}

// Round 3
// 329.318 us; speedup vs baseline: 1.3024x; 1.0510x over previous
//
#include <hip/hip_runtime.h>
#include <hip/hip_bf16.h>

typedef __attribute__((ext_vector_type(8))) short bf16x8;
typedef __attribute__((ext_vector_type(4))) float f32x4;

#define MFMA_BF16(a, b, c) __builtin_amdgcn_mfma_f32_16x16x32_bf16((a), (b), (c), 0, 0, 0)

#define E_DIM 384
#define T_SEQ 256
#define B_BATCH 128
#define H_HEADS 6
#define D_HEAD 64
#define NROWS (B_BATCH * T_SEQ)   // 32768
#define FF_DIM (4 * E_DIM)        // 1536
#define QKV_LD 1152               // 3*E

__device__ __forceinline__ void load_lds16(const __hip_bfloat16* g, __hip_bfloat16* l) {
    __builtin_amdgcn_global_load_lds(
        (const __attribute__((address_space(1))) void*)g,
        (__attribute__((address_space(3))) void*)l, 16, 0, 0);
}

// ---------------------------------------------------------------------------
// All weight transposes + casts in one launch.
// wq|wk|wv: [384][384] -> wqkvT [1152][384]; wp: [384][384] -> wpT [384][384];
// w1: [384][1536] -> w1T [1536][384]; w2: [1536][384] -> w2T [384][1536].
// ---------------------------------------------------------------------------
__global__ void tcast_all_kernel(const float* __restrict__ wq, const float* __restrict__ wk,
                                 const float* __restrict__ wv, const float* __restrict__ wp,
                                 const float* __restrict__ w1, const float* __restrict__ w2,
                                 __hip_bfloat16* __restrict__ wqkvT, __hip_bfloat16* __restrict__ wpT,
                                 __hip_bfloat16* __restrict__ w1T, __hip_bfloat16* __restrict__ w2T) {
    const int WE = E_DIM * E_DIM;   // 147456
    const int FE = E_DIM * FF_DIM;  // 589824
    int idx = blockIdx.x * 256 + threadIdx.x;
    if (idx < 3 * WE) {
        int seg = idx / WE, j = idx - seg * WE;
        const float* W = seg == 0 ? wq : (seg == 1 ? wk : wv);
        int k = j / E_DIM, n = j - k * E_DIM;
        wqkvT[(size_t)seg * WE + (size_t)n * E_DIM + k] = __float2bfloat16(W[j]);
    } else if (idx < 4 * WE) {
        int j = idx - 3 * WE;
        int k = j / E_DIM, n = j - k * E_DIM;
        wpT[(size_t)n * E_DIM + k] = __float2bfloat16(wp[j]);
    } else if (idx < 4 * WE + FE) {
        int j = idx - 4 * WE;
        int k = j / FF_DIM, n = j - k * FF_DIM;
        w1T[(size_t)n * E_DIM + k] = __float2bfloat16(w1[j]);
    } else {
        int j = idx - 4 * WE - FE;
        int k = j / E_DIM, n = j - k * E_DIM;
        w2T[(size_t)n * FF_DIM + k] = __float2bfloat16(w2[j]);
    }
}

// ---------------------------------------------------------------------------
// LayerNorm: x[rows][384] f32 -> out[rows][384] bf16.  One wave per row.
// ---------------------------------------------------------------------------
__global__ __launch_bounds__(256) void ln_kernel(const float* __restrict__ x,
                                                 const float* __restrict__ g,
                                                 const float* __restrict__ bta,
                                                 __hip_bfloat16* __restrict__ out) {
    int row = blockIdx.x * 4 + (threadIdx.x >> 6);
    int lane = threadIdx.x & 63;
    const float* xr = x + (size_t)row * E_DIM;
    float vals[6];
    float s = 0.f;
#pragma unroll
    for (int i = 0; i < 6; i++) {
        vals[i] = xr[lane + i * 64];
        s += vals[i];
    }
#pragma unroll
    for (int off = 1; off < 64; off <<= 1) s += __shfl_xor(s, off, 64);
    float mu = s * (1.f / E_DIM);
    float vv = 0.f;
#pragma unroll
    for (int i = 0; i < 6; i++) {
        float d = vals[i] - mu;
        vv += d * d;
    }
#pragma unroll
    for (int off = 1; off < 64; off <<= 1) vv += __shfl_xor(vv, off, 64);
    float rstd = rsqrtf(vv * (1.f / E_DIM) + 1e-5f);
#pragma unroll
    for (int i = 0; i < 6; i++) {
        int c = lane + i * 64;
        out[(size_t)row * E_DIM + c] =
            __float2bfloat16((vals[i] - mu) * rstd * g[c] + bta[c]);
    }
}

// ---------------------------------------------------------------------------
// GEMM, 2-phase prefetch: C[M][N] = A[M][K] @ BT[N][K]^T, bf16 in, f32 accum.
// Tile 128x128, BK=64, 4 waves (2x2), each wave 64x64 via 4x4 16x16x32 MFMA.
// Double-buffered LDS; next tile's global_load_lds issued BEFORE compute of
// current tile; single __syncthreads per K-step (drain lands after compute).
// EPI: 0 = store bf16; 1 = +bias +f32 residual, store f32; 2 = +bias, relu, bf16
// ---------------------------------------------------------------------------
template <int EPI>
__global__ __launch_bounds__(256) void gemm128_kernel(
    const __hip_bfloat16* __restrict__ A, const __hip_bfloat16* __restrict__ BT,
    const float* __restrict__ bias, const float* __restrict__ resid,
    __hip_bfloat16* __restrict__ outb, float* __restrict__ outf,
    int M, int N, int K) {
    __shared__ __hip_bfloat16 As[2][128 * 64];
    __shared__ __hip_bfloat16 Bs[2][128 * 64];
    const int t = threadIdx.x;
    const int w = t >> 6, lane = t & 63;
    const int l16 = lane & 15, lhi = lane >> 4;
    const int wr = w >> 1, wc = w & 1;

    // XCD-aware chunked swizzle (grid divisible by 8 for all our shapes)
    const int nwg = gridDim.x;
    const int bid = blockIdx.x;
    const int cpx = nwg >> 3;
    const int swz = (bid & 7) * cpx + (bid >> 3);
    const int nb = N >> 7;
    const int m0 = (swz / nb) * 128;
    const int n0 = (swz % nb) * 128;

    // per-thread staging source pointers (advance by 64 per K-step)
    const __hip_bfloat16* pa[4];
    const __hip_bfloat16* pb[4];
    int eoff[4];
#pragma unroll
    for (int i = 0; i < 4; i++) {
        int e = (i * 256 + t) * 8;  // flat bf16 elem in 128x64 tile
        int r = e >> 6, c = e & 63;
        eoff[i] = e;
        pa[i] = A + (size_t)(m0 + r) * K + c;
        pb[i] = BT + (size_t)(n0 + r) * K + c;
    }

    f32x4 acc[4][4] = {};
    const int nk = K >> 6;

    // prologue: stage tile 0 into buf 0
#pragma unroll
    for (int i = 0; i < 4; i++) {
        load_lds16(pa[i], &As[0][eoff[i]]);
        load_lds16(pb[i], &Bs[0][eoff[i]]);
        pa[i] += 64;
        pb[i] += 64;
    }
    __syncthreads();

    int cur = 0;
    for (int kt = 0; kt < nk; kt++) {
        if (kt + 1 < nk) {
#pragma unroll
            for (int i = 0; i < 4; i++) {
                load_lds16(pa[i], &As[cur ^ 1][eoff[i]]);
                load_lds16(pb[i], &Bs[cur ^ 1][eoff[i]]);
                pa[i] += 64;
                pb[i] += 64;
            }
        }
#pragma unroll
        for (int kk = 0; kk < 2; kk++) {
            bf16x8 af[4], bfr[4];
#pragma unroll
            for (int mr = 0; mr < 4; mr++)
                af[mr] = *reinterpret_cast<const bf16x8*>(
                    &As[cur][(wr * 64 + mr * 16 + l16) * 64 + kk * 32 + lhi * 8]);
#pragma unroll
            for (int nr = 0; nr < 4; nr++)
                bfr[nr] = *reinterpret_cast<const bf16x8*>(
                    &Bs[cur][(wc * 64 + nr * 16 + l16) * 64 + kk * 32 + lhi * 8]);
#pragma unroll
            for (int mr = 0; mr < 4; mr++)
#pragma unroll
                for (int nr = 0; nr < 4; nr++)
                    acc[mr][nr] = MFMA_BF16(af[mr], bfr[nr], acc[mr][nr]);
        }
        __syncthreads();  // drains this wave's vmcnt (prefetch) + lds reads
        cur ^= 1;
    }

#pragma unroll
    for (int mr = 0; mr < 4; mr++) {
#pragma unroll
        for (int nr = 0; nr < 4; nr++) {
            int col = n0 + wc * 64 + nr * 16 + l16;
#pragma unroll
            for (int r = 0; r < 4; r++) {
                int row = m0 + wr * 64 + mr * 16 + lhi * 4 + r;
                size_t off = (size_t)row * N + col;
                float v = acc[mr][nr][r];
                if (EPI == 0) {
                    outb[off] = __float2bfloat16(v);
                } else if (EPI == 1) {
                    outf[off] = v + bias[col] + resid[off];
                } else {
                    v += bias[col];
                    outb[off] = __float2bfloat16(v > 0.f ? v : 0.f);
                }
            }
        }
    }
}

// ---------------------------------------------------------------------------
// Causal attention, one block per (b,h). qkv packed [rows][1152].
// ---------------------------------------------------------------------------
__global__ __launch_bounds__(256, 1) void attn_kernel(
    const __hip_bfloat16* __restrict__ qkv, __hip_bfloat16* __restrict__ o) {
    __shared__ __hip_bfloat16 Ks[T_SEQ][72];
    __shared__ __hip_bfloat16 VTs[D_HEAD][272];
    __shared__ __hip_bfloat16 Ps[4][64][72];

    const int bh = blockIdx.x;
    const int b = bh / H_HEADS, h = bh - b * H_HEADS;
    const int t = threadIdx.x;
    const int w = t >> 6, lane = t & 63;
    const int l16 = lane & 15, lhi = lane >> 4;
    const size_t rbase = (size_t)b * T_SEQ;
    const int qoff = h * D_HEAD, koff = E_DIM + h * D_HEAD, voff = 2 * E_DIM + h * D_HEAD;
    const float scale = 0.051031036307982884f;  // 384^-0.5

#pragma unroll
    for (int i = 0; i < 8; i++) {
        int idx = i * 256 + t;
        int r = idx >> 3, c = (idx & 7) * 8;
        *reinterpret_cast<uint4*>(&Ks[r][c]) =
            *reinterpret_cast<const uint4*>(qkv + (rbase + r) * QKV_LD + koff + c);
    }
#pragma unroll
    for (int i = 0; i < 8; i++) {
        int idx = i * 256 + t;
        int r = idx >> 3, d0 = (idx & 7) * 8;
        uint4 val = *reinterpret_cast<const uint4*>(qkv + (rbase + r) * QKV_LD + voff + d0);
        const __hip_bfloat16* p8 = reinterpret_cast<const __hip_bfloat16*>(&val);
#pragma unroll
        for (int j = 0; j < 8; j++) VTs[d0 + j][r] = p8[j];
    }
    __syncthreads();

    bf16x8 qf[4][2];
#pragma unroll
    for (int mr = 0; mr < 4; mr++)
#pragma unroll
        for (int kk = 0; kk < 2; kk++)
            qf[mr][kk] = *reinterpret_cast<const bf16x8*>(
                qkv + (rbase + w * 64 + mr * 16 + l16) * QKV_LD + qoff + kk * 32 + lhi * 8);

    float mstate[4][4], lstate[4][4];
    f32x4 oacc[4][4] = {};
#pragma unroll
    for (int mr = 0; mr < 4; mr++)
#pragma unroll
        for (int r = 0; r < 4; r++) {
            mstate[mr][r] = -INFINITY;
            lstate[mr][r] = 0.f;
        }

    for (int jt = 0; jt <= w; jt++) {
        f32x4 s[4][4] = {};
#pragma unroll
        for (int kk = 0; kk < 2; kk++) {
            bf16x8 kf[4];
#pragma unroll
            for (int nr = 0; nr < 4; nr++)
                kf[nr] = *reinterpret_cast<const bf16x8*>(
                    &Ks[jt * 64 + nr * 16 + l16][kk * 32 + lhi * 8]);
#pragma unroll
            for (int mr = 0; mr < 4; mr++)
#pragma unroll
                for (int nr = 0; nr < 4; nr++)
                    s[mr][nr] = MFMA_BF16(qf[mr][kk], kf[nr], s[mr][nr]);
        }
#pragma unroll
        for (int mr = 0; mr < 4; mr++) {
#pragma unroll
            for (int r = 0; r < 4; r++) {
                int qrow = w * 64 + mr * 16 + lhi * 4 + r;
                float pv[4];
                float mx = -INFINITY;
#pragma unroll
                for (int nr = 0; nr < 4; nr++) {
                    int kcol = jt * 64 + nr * 16 + l16;
                    float val = s[mr][nr][r] * scale;
                    if (kcol > qrow) val = -1e30f;
                    pv[nr] = val;
                    mx = fmaxf(mx, val);
                }
#pragma unroll
                for (int off = 1; off < 16; off <<= 1)
                    mx = fmaxf(mx, __shfl_xor(mx, off, 64));
                float mold = mstate[mr][r];
                float mnew = fmaxf(mold, mx);
                float corr = __expf(mold - mnew);
                float psum = 0.f;
#pragma unroll
                for (int nr = 0; nr < 4; nr++) {
                    float p = __expf(pv[nr] - mnew);
                    pv[nr] = p;
                    psum += p;
                }
#pragma unroll
                for (int off = 1; off < 16; off <<= 1)
                    psum += __shfl_xor(psum, off, 64);
                lstate[mr][r] = lstate[mr][r] * corr + psum;
                mstate[mr][r] = mnew;
#pragma unroll
                for (int dr = 0; dr < 4; dr++) oacc[mr][dr][r] *= corr;
#pragma unroll
                for (int nr = 0; nr < 4; nr++)
                    Ps[w][mr * 16 + lhi * 4 + r][nr * 16 + l16] = __float2bfloat16(pv[nr]);
            }
        }
#pragma unroll
        for (int kk = 0; kk < 2; kk++) {
            bf16x8 pa[4], vbf[4];
#pragma unroll
            for (int mr = 0; mr < 4; mr++)
                pa[mr] = *reinterpret_cast<const bf16x8*>(
                    &Ps[w][mr * 16 + l16][kk * 32 + lhi * 8]);
#pragma unroll
            for (int dr = 0; dr < 4; dr++)
                vbf[dr] = *reinterpret_cast<const bf16x8*>(
                    &VTs[dr * 16 + l16][jt * 64 + kk * 32 + lhi * 8]);
#pragma unroll
            for (int mr = 0; mr < 4; mr++)
#pragma unroll
                for (int dr = 0; dr < 4; dr++)
                    oacc[mr][dr] = MFMA_BF16(pa[mr], vbf[dr], oacc[mr][dr]);
        }
    }

#pragma unroll
    for (int mr = 0; mr < 4; mr++) {
#pragma unroll
        for (int r = 0; r < 4; r++) {
            float rl = 1.f / lstate[mr][r];
            int row = w * 64 + mr * 16 + lhi * 4 + r;
#pragma unroll
            for (int dr = 0; dr < 4; dr++)
                o[(rbase + row) * E_DIM + h * D_HEAD + dr * 16 + l16] =
                    __float2bfloat16(oacc[mr][dr][r] * rl);
        }
    }
}

// ---------------------------------------------------------------------------
extern "C" void kernel_launch(void* const* d_in, const int* in_sizes, int n_in,
                              void* d_out, int out_size, void* d_ws, size_t ws_size,
                              hipStream_t stream) {
    const float* x      = (const float*)d_in[0];
    const float* wq     = (const float*)d_in[1];
    const float* wk     = (const float*)d_in[2];
    const float* wv     = (const float*)d_in[3];
    const float* w_proj = (const float*)d_in[4];
    const float* b_proj = (const float*)d_in[5];
    const float* w1     = (const float*)d_in[6];
    const float* b1     = (const float*)d_in[7];
    const float* w2     = (const float*)d_in[8];
    const float* b2     = (const float*)d_in[9];
    const float* g1     = (const float*)d_in[10];
    const float* bt1    = (const float*)d_in[11];
    const float* g2     = (const float*)d_in[12];
    const float* bt2    = (const float*)d_in[13];
    float* out = (float*)d_out;

    char* ws = (char*)d_ws;
    size_t off = 0;
    auto alloc = [&](size_t bytes) {
        void* p = ws + off;
        off += (bytes + 255) & ~(size_t)255;
        return p;
    };
    const size_t wElems = E_DIM * E_DIM;
    const size_t fElems = E_DIM * FF_DIM;
    const size_t actElems = (size_t)NROWS * E_DIM;
    __hip_bfloat16* wqkvT = (__hip_bfloat16*)alloc(3 * wElems * 2);  // [1152][384]
    __hip_bfloat16* wpT   = (__hip_bfloat16*)alloc(wElems * 2);
    __hip_bfloat16* w1T   = (__hip_bfloat16*)alloc(fElems * 2);
    __hip_bfloat16* w2T   = (__hip_bfloat16*)alloc(fElems * 2);
    __hip_bfloat16* lnb   = (__hip_bfloat16*)alloc(actElems * 2);      // ln1 / ln2
    __hip_bfloat16* qkv   = (__hip_bfloat16*)alloc(3 * actElems * 2);  // [32768][1152]
    __hip_bfloat16* ab    = (__hip_bfloat16*)alloc(actElems * 2);      // attn out
    __hip_bfloat16* h1    = qkv;  // FFN hidden (96MB) reuses qkv+ab space
    float* x2 = out;

    // 1) all weights -> bf16 transposed, one launch
    tcast_all_kernel<<<6912, 256, 0, stream>>>(wq, wk, wv, w_proj, w1, w2,
                                               wqkvT, wpT, w1T, w2T);

    // 2) ln1
    ln_kernel<<<NROWS / 4, 256, 0, stream>>>(x, g1, bt1, lnb);

    // 3) fused qkv: [32768][1152]
    gemm128_kernel<0><<<(NROWS / 128) * (QKV_LD / 128), 256, 0, stream>>>(
        lnb, wqkvT, nullptr, nullptr, qkv, nullptr, NROWS, QKV_LD, E_DIM);

    // 4) attention
    attn_kernel<<<B_BATCH * H_HEADS, 256, 0, stream>>>(qkv, ab);

    // 5) x2 = x + attn @ w_proj + b_proj  (f32, in d_out)
    gemm128_kernel<1><<<(NROWS / 128) * (E_DIM / 128), 256, 0, stream>>>(
        ab, wpT, b_proj, x, nullptr, x2, NROWS, E_DIM, E_DIM);

    // 6) ln2
    ln_kernel<<<NROWS / 4, 256, 0, stream>>>(x2, g2, bt2, lnb);

    // 7) h1 = relu(ln2 @ w1 + b1)
    gemm128_kernel<2><<<(NROWS / 128) * (FF_DIM / 128), 256, 0, stream>>>(
        lnb, w1T, b1, nullptr, h1, nullptr, NROWS, FF_DIM, E_DIM);

    // 8) out = x2 + h1 @ w2 + b2
    gemm128_kernel<1><<<(NROWS / 128) * (E_DIM / 128), 256, 0, stream>>>(
        h1, w2T, b2, x2, nullptr, out, NROWS, E_DIM, FF_DIM);
}

// Round 4
// 287.519 us; speedup vs baseline: 1.4918x; 1.1454x over previous
//
#include <hip/hip_runtime.h>
#include <hip/hip_bf16.h>

typedef __attribute__((ext_vector_type(8))) short bf16x8;
typedef __attribute__((ext_vector_type(4))) float f32x4;

#define MFMA_BF16(a, b, c) __builtin_amdgcn_mfma_f32_16x16x32_bf16((a), (b), (c), 0, 0, 0)

#define E_DIM 384
#define T_SEQ 256
#define B_BATCH 128
#define H_HEADS 6
#define D_HEAD 64
#define NROWS (B_BATCH * T_SEQ)   // 32768
#define FF_DIM (4 * E_DIM)        // 1536
#define QKV_LD 1152               // 3*E

__device__ __forceinline__ void load_lds16(const __hip_bfloat16* g, __hip_bfloat16* l) {
    __builtin_amdgcn_global_load_lds(
        (const __attribute__((address_space(1))) void*)g,
        (__attribute__((address_space(3))) void*)l, 16, 0, 0);
}

// ---------------------------------------------------------------------------
// All weight transposes + casts in one launch.
// ---------------------------------------------------------------------------
__global__ void tcast_all_kernel(const float* __restrict__ wq, const float* __restrict__ wk,
                                 const float* __restrict__ wv, const float* __restrict__ wp,
                                 const float* __restrict__ w1, const float* __restrict__ w2,
                                 __hip_bfloat16* __restrict__ wqkvT, __hip_bfloat16* __restrict__ wpT,
                                 __hip_bfloat16* __restrict__ w1T, __hip_bfloat16* __restrict__ w2T) {
    const int WE = E_DIM * E_DIM;   // 147456
    const int FE = E_DIM * FF_DIM;  // 589824
    int idx = blockIdx.x * 256 + threadIdx.x;
    if (idx < 3 * WE) {
        int seg = idx / WE, j = idx - seg * WE;
        const float* W = seg == 0 ? wq : (seg == 1 ? wk : wv);
        int k = j / E_DIM, n = j - k * E_DIM;
        wqkvT[(size_t)seg * WE + (size_t)n * E_DIM + k] = __float2bfloat16(W[j]);
    } else if (idx < 4 * WE) {
        int j = idx - 3 * WE;
        int k = j / E_DIM, n = j - k * E_DIM;
        wpT[(size_t)n * E_DIM + k] = __float2bfloat16(wp[j]);
    } else if (idx < 4 * WE + FE) {
        int j = idx - 4 * WE;
        int k = j / FF_DIM, n = j - k * FF_DIM;
        w1T[(size_t)n * E_DIM + k] = __float2bfloat16(w1[j]);
    } else {
        int j = idx - 4 * WE - FE;
        int k = j / E_DIM, n = j - k * E_DIM;
        w2T[(size_t)n * FF_DIM + k] = __float2bfloat16(w2[j]);
    }
}

// ---------------------------------------------------------------------------
// LayerNorm: x[rows][384] f32 -> out[rows][384] bf16.  One wave per row.
// ---------------------------------------------------------------------------
__global__ __launch_bounds__(256) void ln_kernel(const float* __restrict__ x,
                                                 const float* __restrict__ g,
                                                 const float* __restrict__ bta,
                                                 __hip_bfloat16* __restrict__ out) {
    int row = blockIdx.x * 4 + (threadIdx.x >> 6);
    int lane = threadIdx.x & 63;
    const float* xr = x + (size_t)row * E_DIM;
    float vals[6];
    float s = 0.f;
#pragma unroll
    for (int i = 0; i < 6; i++) {
        vals[i] = xr[lane + i * 64];
        s += vals[i];
    }
#pragma unroll
    for (int off = 1; off < 64; off <<= 1) s += __shfl_xor(s, off, 64);
    float mu = s * (1.f / E_DIM);
    float vv = 0.f;
#pragma unroll
    for (int i = 0; i < 6; i++) {
        float d = vals[i] - mu;
        vv += d * d;
    }
#pragma unroll
    for (int off = 1; off < 64; off <<= 1) vv += __shfl_xor(vv, off, 64);
    float rstd = rsqrtf(vv * (1.f / E_DIM) + 1e-5f);
#pragma unroll
    for (int i = 0; i < 6; i++) {
        int c = lane + i * 64;
        out[(size_t)row * E_DIM + c] =
            __float2bfloat16((vals[i] - mu) * rstd * g[c] + bta[c]);
    }
}

// ---------------------------------------------------------------------------
// Pipelined GEMM: C[M][N] = A[M][K] @ BT[N][K]^T, bf16 in, f32 accum.
// BM=256, BN=128, BK=64. 512 threads = 8 waves (4M x 2N), wave tile 64x64.
// Triple-buffered LDS (3 x 48KB), prefetch 2 K-steps ahead (6 chunks/step),
// counted s_waitcnt vmcnt(6) (never 0 mid-loop), raw s_barrier 1x/step.
// T2 XOR swizzle: LDS linear, global source pre-swizzled, ds_read swizzled.
// EPI: 0 = store bf16; 1 = +bias +f32 residual, store f32; 2 = +bias, relu, bf16
// ---------------------------------------------------------------------------
template <int EPI>
__global__ __launch_bounds__(512, 2) void gemm256_kernel(
    const __hip_bfloat16* __restrict__ A, const __hip_bfloat16* __restrict__ BT,
    const float* __restrict__ bias, const float* __restrict__ resid,
    __hip_bfloat16* __restrict__ outb, float* __restrict__ outf,
    int M, int N, int K) {
    // per buffer: A 256x64 (16384 elems) then B 128x64 (8192 elems)
    __shared__ __hip_bfloat16 lds[3 * 24576];
    const int t = threadIdx.x;
    const int w = t >> 6, lane = t & 63;
    const int l16 = lane & 15, lhi = lane >> 4;
    const int wm = w >> 1, wn = w & 1;

    // XCD-aware chunked swizzle (grids all divisible by 8)
    const int nwg = gridDim.x;
    const int bid = blockIdx.x;
    const int cpx = nwg >> 3;
    const int swz = (bid & 7) * cpx + (bid >> 3);
    const int nb = N >> 7;
    const int m0 = (swz / nb) * 256;
    const int n0 = (swz % nb) * 128;

    // ---- staging setup: 6 chunks of 8KB (512 lanes x 16B) per K-step ----
    const int srow = t >> 3;                        // 0..63 row within chunk
    const int sslot = t & 7;                        // 16B slot within row
    const int scol = ((sslot ^ (srow & 7)) << 3);   // pre-swizzled global col
    const __hip_bfloat16* pa[4];
    const __hip_bfloat16* pb[2];
#pragma unroll
    for (int ci = 0; ci < 4; ci++)
        pa[ci] = A + (size_t)(m0 + ci * 64 + srow) * K + scol;
#pragma unroll
    for (int ci = 0; ci < 2; ci++)
        pb[ci] = BT + (size_t)(n0 + ci * 64 + srow) * K + scol;
    const int dstA = t * 8;          // elem offset of this thread's 16B in chunk
    // ---- swizzled ds_read offsets (elems), compile-time indexed ----
    int aoff[2][4], boff[2][4];
    const int xorv = (l16 & 7) << 4;
#pragma unroll
    for (int kk = 0; kk < 2; kk++) {
#pragma unroll
        for (int mr = 0; mr < 4; mr++) {
            int R = wm * 64 + mr * 16 + l16;
            aoff[kk][mr] = (R * 128 + ((kk * 64 + lhi * 16) ^ xorv)) >> 1;
        }
#pragma unroll
        for (int nr = 0; nr < 4; nr++) {
            int R = wn * 64 + nr * 16 + l16;
            boff[kk][nr] = 16384 + ((R * 128 + ((kk * 64 + lhi * 16) ^ xorv)) >> 1);
        }
    }

    f32x4 acc[4][4] = {};
    const int nk = K >> 6;

#define STAGE(sbuf)                                                           \
    {                                                                         \
        __hip_bfloat16* sbase = &lds[(sbuf) * 24576];                         \
        _Pragma("unroll") for (int ci = 0; ci < 4; ci++) {                    \
            load_lds16(pa[ci], sbase + ci * 4096 + dstA);                     \
            pa[ci] += 64;                                                     \
        }                                                                     \
        _Pragma("unroll") for (int ci = 0; ci < 2; ci++) {                    \
            load_lds16(pb[ci], sbase + 16384 + ci * 4096 + dstA);             \
            pb[ci] += 64;                                                     \
        }                                                                     \
    }

    // prologue: steps 0,1 -> bufs 0,1
    STAGE(0);
    STAGE(1);
    int rb = 0, sb = 2;

    for (int kt = 0; kt < nk; kt++) {
        if (kt + 1 < nk) {
            asm volatile("s_waitcnt vmcnt(6)" ::: "memory");
        } else {
            asm volatile("s_waitcnt vmcnt(0)" ::: "memory");
        }
        __builtin_amdgcn_s_barrier();
        __builtin_amdgcn_sched_barrier(0);
        if (kt + 2 < nk) STAGE(sb);
        const __hip_bfloat16* base = &lds[rb * 24576];
#pragma unroll
        for (int kk = 0; kk < 2; kk++) {
            bf16x8 af[4], bg[4];
#pragma unroll
            for (int mr = 0; mr < 4; mr++)
                af[mr] = *reinterpret_cast<const bf16x8*>(base + aoff[kk][mr]);
#pragma unroll
            for (int nr = 0; nr < 4; nr++)
                bg[nr] = *reinterpret_cast<const bf16x8*>(base + boff[kk][nr]);
            __builtin_amdgcn_s_setprio(1);
#pragma unroll
            for (int mr = 0; mr < 4; mr++)
#pragma unroll
                for (int nr = 0; nr < 4; nr++)
                    acc[mr][nr] = MFMA_BF16(af[mr], bg[nr], acc[mr][nr]);
            __builtin_amdgcn_s_setprio(0);
        }
        rb = rb == 2 ? 0 : rb + 1;
        sb = sb == 2 ? 0 : sb + 1;
    }
#undef STAGE

#pragma unroll
    for (int mr = 0; mr < 4; mr++) {
#pragma unroll
        for (int nr = 0; nr < 4; nr++) {
            int col = n0 + wn * 64 + nr * 16 + l16;
#pragma unroll
            for (int r = 0; r < 4; r++) {
                int row = m0 + wm * 64 + mr * 16 + lhi * 4 + r;
                size_t off = (size_t)row * N + col;
                float v = acc[mr][nr][r];
                if (EPI == 0) {
                    outb[off] = __float2bfloat16(v);
                } else if (EPI == 1) {
                    outf[off] = v + bias[col] + resid[off];
                } else {
                    v += bias[col];
                    outb[off] = __float2bfloat16(v > 0.f ? v : 0.f);
                }
            }
        }
    }
}

// ---------------------------------------------------------------------------
// Causal attention, one block per (b,h). qkv packed [rows][1152].
// ---------------------------------------------------------------------------
__global__ __launch_bounds__(256, 1) void attn_kernel(
    const __hip_bfloat16* __restrict__ qkv, __hip_bfloat16* __restrict__ o) {
    __shared__ __hip_bfloat16 Ks[T_SEQ][72];
    __shared__ __hip_bfloat16 VTs[D_HEAD][272];
    __shared__ __hip_bfloat16 Ps[4][64][72];

    const int bh = blockIdx.x;
    const int b = bh / H_HEADS, h = bh - b * H_HEADS;
    const int t = threadIdx.x;
    const int w = t >> 6, lane = t & 63;
    const int l16 = lane & 15, lhi = lane >> 4;
    const size_t rbase = (size_t)b * T_SEQ;
    const int qoff = h * D_HEAD, koff = E_DIM + h * D_HEAD, voff = 2 * E_DIM + h * D_HEAD;
    const float scale = 0.051031036307982884f;  // 384^-0.5

#pragma unroll
    for (int i = 0; i < 8; i++) {
        int idx = i * 256 + t;
        int r = idx >> 3, c = (idx & 7) * 8;
        *reinterpret_cast<uint4*>(&Ks[r][c]) =
            *reinterpret_cast<const uint4*>(qkv + (rbase + r) * QKV_LD + koff + c);
    }
#pragma unroll
    for (int i = 0; i < 8; i++) {
        int idx = i * 256 + t;
        int r = idx >> 3, d0 = (idx & 7) * 8;
        uint4 val = *reinterpret_cast<const uint4*>(qkv + (rbase + r) * QKV_LD + voff + d0);
        const __hip_bfloat16* p8 = reinterpret_cast<const __hip_bfloat16*>(&val);
#pragma unroll
        for (int j = 0; j < 8; j++) VTs[d0 + j][r] = p8[j];
    }
    __syncthreads();

    bf16x8 qf[4][2];
#pragma unroll
    for (int mr = 0; mr < 4; mr++)
#pragma unroll
        for (int kk = 0; kk < 2; kk++)
            qf[mr][kk] = *reinterpret_cast<const bf16x8*>(
                qkv + (rbase + w * 64 + mr * 16 + l16) * QKV_LD + qoff + kk * 32 + lhi * 8);

    float mstate[4][4], lstate[4][4];
    f32x4 oacc[4][4] = {};
#pragma unroll
    for (int mr = 0; mr < 4; mr++)
#pragma unroll
        for (int r = 0; r < 4; r++) {
            mstate[mr][r] = -INFINITY;
            lstate[mr][r] = 0.f;
        }

    for (int jt = 0; jt <= w; jt++) {
        f32x4 s[4][4] = {};
#pragma unroll
        for (int kk = 0; kk < 2; kk++) {
            bf16x8 kf[4];
#pragma unroll
            for (int nr = 0; nr < 4; nr++)
                kf[nr] = *reinterpret_cast<const bf16x8*>(
                    &Ks[jt * 64 + nr * 16 + l16][kk * 32 + lhi * 8]);
#pragma unroll
            for (int mr = 0; mr < 4; mr++)
#pragma unroll
                for (int nr = 0; nr < 4; nr++)
                    s[mr][nr] = MFMA_BF16(qf[mr][kk], kf[nr], s[mr][nr]);
        }
#pragma unroll
        for (int mr = 0; mr < 4; mr++) {
#pragma unroll
            for (int r = 0; r < 4; r++) {
                int qrow = w * 64 + mr * 16 + lhi * 4 + r;
                float pv[4];
                float mx = -INFINITY;
#pragma unroll
                for (int nr = 0; nr < 4; nr++) {
                    int kcol = jt * 64 + nr * 16 + l16;
                    float val = s[mr][nr][r] * scale;
                    if (kcol > qrow) val = -1e30f;
                    pv[nr] = val;
                    mx = fmaxf(mx, val);
                }
#pragma unroll
                for (int off = 1; off < 16; off <<= 1)
                    mx = fmaxf(mx, __shfl_xor(mx, off, 64));
                float mold = mstate[mr][r];
                float mnew = fmaxf(mold, mx);
                float corr = __expf(mold - mnew);
                float psum = 0.f;
#pragma unroll
                for (int nr = 0; nr < 4; nr++) {
                    float p = __expf(pv[nr] - mnew);
                    pv[nr] = p;
                    psum += p;
                }
#pragma unroll
                for (int off = 1; off < 16; off <<= 1)
                    psum += __shfl_xor(psum, off, 64);
                lstate[mr][r] = lstate[mr][r] * corr + psum;
                mstate[mr][r] = mnew;
#pragma unroll
                for (int dr = 0; dr < 4; dr++) oacc[mr][dr][r] *= corr;
#pragma unroll
                for (int nr = 0; nr < 4; nr++)
                    Ps[w][mr * 16 + lhi * 4 + r][nr * 16 + l16] = __float2bfloat16(pv[nr]);
            }
        }
#pragma unroll
        for (int kk = 0; kk < 2; kk++) {
            bf16x8 pa[4], vbf[4];
#pragma unroll
            for (int mr = 0; mr < 4; mr++)
                pa[mr] = *reinterpret_cast<const bf16x8*>(
                    &Ps[w][mr * 16 + l16][kk * 32 + lhi * 8]);
#pragma unroll
            for (int dr = 0; dr < 4; dr++)
                vbf[dr] = *reinterpret_cast<const bf16x8*>(
                    &VTs[dr * 16 + l16][jt * 64 + kk * 32 + lhi * 8]);
#pragma unroll
            for (int mr = 0; mr < 4; mr++)
#pragma unroll
                for (int dr = 0; dr < 4; dr++)
                    oacc[mr][dr] = MFMA_BF16(pa[mr], vbf[dr], oacc[mr][dr]);
        }
    }

#pragma unroll
    for (int mr = 0; mr < 4; mr++) {
#pragma unroll
        for (int r = 0; r < 4; r++) {
            float rl = 1.f / lstate[mr][r];
            int row = w * 64 + mr * 16 + lhi * 4 + r;
#pragma unroll
            for (int dr = 0; dr < 4; dr++)
                o[(rbase + row) * E_DIM + h * D_HEAD + dr * 16 + l16] =
                    __float2bfloat16(oacc[mr][dr][r] * rl);
        }
    }
}

// ---------------------------------------------------------------------------
extern "C" void kernel_launch(void* const* d_in, const int* in_sizes, int n_in,
                              void* d_out, int out_size, void* d_ws, size_t ws_size,
                              hipStream_t stream) {
    const float* x      = (const float*)d_in[0];
    const float* wq     = (const float*)d_in[1];
    const float* wk     = (const float*)d_in[2];
    const float* wv     = (const float*)d_in[3];
    const float* w_proj = (const float*)d_in[4];
    const float* b_proj = (const float*)d_in[5];
    const float* w1     = (const float*)d_in[6];
    const float* b1     = (const float*)d_in[7];
    const float* w2     = (const float*)d_in[8];
    const float* b2     = (const float*)d_in[9];
    const float* g1     = (const float*)d_in[10];
    const float* bt1    = (const float*)d_in[11];
    const float* g2     = (const float*)d_in[12];
    const float* bt2    = (const float*)d_in[13];
    float* out = (float*)d_out;

    char* ws = (char*)d_ws;
    size_t off = 0;
    auto alloc = [&](size_t bytes) {
        void* p = ws + off;
        off += (bytes + 255) & ~(size_t)255;
        return p;
    };
    const size_t wElems = E_DIM * E_DIM;
    const size_t fElems = E_DIM * FF_DIM;
    const size_t actElems = (size_t)NROWS * E_DIM;
    __hip_bfloat16* wqkvT = (__hip_bfloat16*)alloc(3 * wElems * 2);  // [1152][384]
    __hip_bfloat16* wpT   = (__hip_bfloat16*)alloc(wElems * 2);
    __hip_bfloat16* w1T   = (__hip_bfloat16*)alloc(fElems * 2);
    __hip_bfloat16* w2T   = (__hip_bfloat16*)alloc(fElems * 2);
    __hip_bfloat16* lnb   = (__hip_bfloat16*)alloc(actElems * 2);      // ln1 / ln2
    __hip_bfloat16* qkv   = (__hip_bfloat16*)alloc(3 * actElems * 2);  // [32768][1152]
    __hip_bfloat16* ab    = (__hip_bfloat16*)alloc(actElems * 2);      // attn out
    __hip_bfloat16* h1    = qkv;  // FFN hidden (96MB) reuses qkv+ab space
    float* x2 = out;

    // 1) all weights -> bf16 transposed, one launch
    tcast_all_kernel<<<6912, 256, 0, stream>>>(wq, wk, wv, w_proj, w1, w2,
                                               wqkvT, wpT, w1T, w2T);

    // 2) ln1
    ln_kernel<<<NROWS / 4, 256, 0, stream>>>(x, g1, bt1, lnb);

    // 3) fused qkv: [32768][1152]
    gemm256_kernel<0><<<(NROWS / 256) * (QKV_LD / 128), 512, 0, stream>>>(
        lnb, wqkvT, nullptr, nullptr, qkv, nullptr, NROWS, QKV_LD, E_DIM);

    // 4) attention
    attn_kernel<<<B_BATCH * H_HEADS, 256, 0, stream>>>(qkv, ab);

    // 5) x2 = x + attn @ w_proj + b_proj  (f32, in d_out)
    gemm256_kernel<1><<<(NROWS / 256) * (E_DIM / 128), 512, 0, stream>>>(
        ab, wpT, b_proj, x, nullptr, x2, NROWS, E_DIM, E_DIM);

    // 6) ln2
    ln_kernel<<<NROWS / 4, 256, 0, stream>>>(x2, g2, bt2, lnb);

    // 7) h1 = relu(ln2 @ w1 + b1)
    gemm256_kernel<2><<<(NROWS / 256) * (FF_DIM / 128), 512, 0, stream>>>(
        lnb, w1T, b1, nullptr, h1, nullptr, NROWS, FF_DIM, E_DIM);

    // 8) out = x2 + h1 @ w2 + b2
    gemm256_kernel<1><<<(NROWS / 256) * (E_DIM / 128), 512, 0, stream>>>(
        h1, w2T, b2, x2, nullptr, out, NROWS, E_DIM, FF_DIM);
}

// Round 5
// 272.199 us; speedup vs baseline: 1.5758x; 1.0563x over previous
//
#include <hip/hip_runtime.h>
#include <hip/hip_bf16.h>

typedef __attribute__((ext_vector_type(8))) short bf16x8;
typedef __attribute__((ext_vector_type(4))) float f32x4;

#define MFMA_BF16(a, b, c) __builtin_amdgcn_mfma_f32_16x16x32_bf16((a), (b), (c), 0, 0, 0)

#define E_DIM 384
#define T_SEQ 256
#define B_BATCH 128
#define H_HEADS 6
#define D_HEAD 64
#define NROWS (B_BATCH * T_SEQ)   // 32768
#define FF_DIM (4 * E_DIM)        // 1536
#define QKV_LD 1152               // 3*E

__device__ __forceinline__ void load_lds16(const __hip_bfloat16* g, __hip_bfloat16* l) {
    __builtin_amdgcn_global_load_lds(
        (const __attribute__((address_space(1))) void*)g,
        (__attribute__((address_space(3))) void*)l, 16, 0, 0);
}

// ---------------------------------------------------------------------------
// All weight transposes + casts in one launch.
// ---------------------------------------------------------------------------
__global__ void tcast_all_kernel(const float* __restrict__ wq, const float* __restrict__ wk,
                                 const float* __restrict__ wv, const float* __restrict__ wp,
                                 const float* __restrict__ w1, const float* __restrict__ w2,
                                 __hip_bfloat16* __restrict__ wqkvT, __hip_bfloat16* __restrict__ wpT,
                                 __hip_bfloat16* __restrict__ w1T, __hip_bfloat16* __restrict__ w2T) {
    const int WE = E_DIM * E_DIM;   // 147456
    const int FE = E_DIM * FF_DIM;  // 589824
    int idx = blockIdx.x * 256 + threadIdx.x;
    if (idx < 3 * WE) {
        int seg = idx / WE, j = idx - seg * WE;
        const float* W = seg == 0 ? wq : (seg == 1 ? wk : wv);
        int k = j / E_DIM, n = j - k * E_DIM;
        wqkvT[(size_t)seg * WE + (size_t)n * E_DIM + k] = __float2bfloat16(W[j]);
    } else if (idx < 4 * WE) {
        int j = idx - 3 * WE;
        int k = j / E_DIM, n = j - k * E_DIM;
        wpT[(size_t)n * E_DIM + k] = __float2bfloat16(wp[j]);
    } else if (idx < 4 * WE + FE) {
        int j = idx - 4 * WE;
        int k = j / FF_DIM, n = j - k * FF_DIM;
        w1T[(size_t)n * E_DIM + k] = __float2bfloat16(w1[j]);
    } else {
        int j = idx - 4 * WE - FE;
        int k = j / E_DIM, n = j - k * E_DIM;
        w2T[(size_t)n * FF_DIM + k] = __float2bfloat16(w2[j]);
    }
}

// ---------------------------------------------------------------------------
// LayerNorm: x[rows][384] f32 -> out[rows][384] bf16.  One wave per row.
// ---------------------------------------------------------------------------
__global__ __launch_bounds__(256) void ln_kernel(const float* __restrict__ x,
                                                 const float* __restrict__ g,
                                                 const float* __restrict__ bta,
                                                 __hip_bfloat16* __restrict__ out) {
    int row = blockIdx.x * 4 + (threadIdx.x >> 6);
    int lane = threadIdx.x & 63;
    const float* xr = x + (size_t)row * E_DIM;
    float vals[6];
    float s = 0.f;
#pragma unroll
    for (int i = 0; i < 6; i++) {
        vals[i] = xr[lane + i * 64];
        s += vals[i];
    }
#pragma unroll
    for (int off = 1; off < 64; off <<= 1) s += __shfl_xor(s, off, 64);
    float mu = s * (1.f / E_DIM);
    float vv = 0.f;
#pragma unroll
    for (int i = 0; i < 6; i++) {
        float d = vals[i] - mu;
        vv += d * d;
    }
#pragma unroll
    for (int off = 1; off < 64; off <<= 1) vv += __shfl_xor(vv, off, 64);
    float rstd = rsqrtf(vv * (1.f / E_DIM) + 1e-5f);
#pragma unroll
    for (int i = 0; i < 6; i++) {
        int c = lane + i * 64;
        out[(size_t)row * E_DIM + c] =
            __float2bfloat16((vals[i] - mu) * rstd * g[c] + bta[c]);
    }
}

// ---------------------------------------------------------------------------
// Pipelined GEMM: C[M][N] = A[M][K] @ BT[N][K]^T, bf16 in, f32 accum.
// BM=256, BN=128, BK=64. 512 threads = 8 waves (4M x 2N), wave tile 64x64.
// Triple-buffered LDS, counted vmcnt(6), raw s_barrier, T2 swizzle, T5 setprio.
// EPI: 0 = store bf16; 1 = +bias +f32 residual, store f32; 2 = +bias, relu, bf16
// ---------------------------------------------------------------------------
template <int EPI>
__global__ __launch_bounds__(512, 2) void gemm256_kernel(
    const __hip_bfloat16* __restrict__ A, const __hip_bfloat16* __restrict__ BT,
    const float* __restrict__ bias, const float* __restrict__ resid,
    __hip_bfloat16* __restrict__ outb, float* __restrict__ outf,
    int M, int N, int K) {
    __shared__ __hip_bfloat16 lds[3 * 24576];
    const int t = threadIdx.x;
    const int w = t >> 6, lane = t & 63;
    const int l16 = lane & 15, lhi = lane >> 4;
    const int wm = w >> 1, wn = w & 1;

    const int nwg = gridDim.x;
    const int bid = blockIdx.x;
    const int cpx = nwg >> 3;
    const int swz = (bid & 7) * cpx + (bid >> 3);
    const int nb = N >> 7;
    const int m0 = (swz / nb) * 256;
    const int n0 = (swz % nb) * 128;

    const int srow = t >> 3;
    const int sslot = t & 7;
    const int scol = ((sslot ^ (srow & 7)) << 3);
    const __hip_bfloat16* pa[4];
    const __hip_bfloat16* pb[2];
#pragma unroll
    for (int ci = 0; ci < 4; ci++)
        pa[ci] = A + (size_t)(m0 + ci * 64 + srow) * K + scol;
#pragma unroll
    for (int ci = 0; ci < 2; ci++)
        pb[ci] = BT + (size_t)(n0 + ci * 64 + srow) * K + scol;
    const int dstA = t * 8;
    int aoff[2][4], boff[2][4];
    const int xorv = (l16 & 7) << 4;
#pragma unroll
    for (int kk = 0; kk < 2; kk++) {
#pragma unroll
        for (int mr = 0; mr < 4; mr++) {
            int R = wm * 64 + mr * 16 + l16;
            aoff[kk][mr] = (R * 128 + ((kk * 64 + lhi * 16) ^ xorv)) >> 1;
        }
#pragma unroll
        for (int nr = 0; nr < 4; nr++) {
            int R = wn * 64 + nr * 16 + l16;
            boff[kk][nr] = 16384 + ((R * 128 + ((kk * 64 + lhi * 16) ^ xorv)) >> 1);
        }
    }

    f32x4 acc[4][4] = {};
    const int nk = K >> 6;

#define STAGE(sbuf)                                                           \
    {                                                                         \
        __hip_bfloat16* sbase = &lds[(sbuf) * 24576];                         \
        _Pragma("unroll") for (int ci = 0; ci < 4; ci++) {                    \
            load_lds16(pa[ci], sbase + ci * 4096 + dstA);                     \
            pa[ci] += 64;                                                     \
        }                                                                     \
        _Pragma("unroll") for (int ci = 0; ci < 2; ci++) {                    \
            load_lds16(pb[ci], sbase + 16384 + ci * 4096 + dstA);             \
            pb[ci] += 64;                                                     \
        }                                                                     \
    }

    STAGE(0);
    STAGE(1);
    int rb = 0, sb = 2;

    for (int kt = 0; kt < nk; kt++) {
        if (kt + 1 < nk) {
            asm volatile("s_waitcnt vmcnt(6)" ::: "memory");
        } else {
            asm volatile("s_waitcnt vmcnt(0)" ::: "memory");
        }
        __builtin_amdgcn_s_barrier();
        __builtin_amdgcn_sched_barrier(0);
        if (kt + 2 < nk) STAGE(sb);
        const __hip_bfloat16* base = &lds[rb * 24576];
#pragma unroll
        for (int kk = 0; kk < 2; kk++) {
            bf16x8 af[4], bg[4];
#pragma unroll
            for (int mr = 0; mr < 4; mr++)
                af[mr] = *reinterpret_cast<const bf16x8*>(base + aoff[kk][mr]);
#pragma unroll
            for (int nr = 0; nr < 4; nr++)
                bg[nr] = *reinterpret_cast<const bf16x8*>(base + boff[kk][nr]);
            __builtin_amdgcn_s_setprio(1);
#pragma unroll
            for (int mr = 0; mr < 4; mr++)
#pragma unroll
                for (int nr = 0; nr < 4; nr++)
                    acc[mr][nr] = MFMA_BF16(af[mr], bg[nr], acc[mr][nr]);
            __builtin_amdgcn_s_setprio(0);
        }
        rb = rb == 2 ? 0 : rb + 1;
        sb = sb == 2 ? 0 : sb + 1;
    }
#undef STAGE

#pragma unroll
    for (int mr = 0; mr < 4; mr++) {
#pragma unroll
        for (int nr = 0; nr < 4; nr++) {
            int col = n0 + wn * 64 + nr * 16 + l16;
#pragma unroll
            for (int r = 0; r < 4; r++) {
                int row = m0 + wm * 64 + mr * 16 + lhi * 4 + r;
                size_t off = (size_t)row * N + col;
                float v = acc[mr][nr][r];
                if (EPI == 0) {
                    outb[off] = __float2bfloat16(v);
                } else if (EPI == 1) {
                    outf[off] = v + bias[col] + resid[off];
                } else {
                    v += bias[col];
                    outb[off] = __float2bfloat16(v > 0.f ? v : 0.f);
                }
            }
        }
    }
}

// ---------------------------------------------------------------------------
// Causal attention, one block per (b,h). qkv packed [rows][1152].
// 8 waves (512 thr); wave w owns Q rows 32w..32w+31, iterates jt=0..(w>>1).
// exp2-domain online softmax; diagonal-tile-only masking.
// ---------------------------------------------------------------------------
__global__ __launch_bounds__(512, 1) void attn_kernel(
    const __hip_bfloat16* __restrict__ qkv, __hip_bfloat16* __restrict__ o) {
    __shared__ __hip_bfloat16 Ks[T_SEQ][72];     // 36.9 KB
    __shared__ __hip_bfloat16 VTs[D_HEAD][264];  // 33.8 KB
    __shared__ __hip_bfloat16 Ps[8][32][72];     // 36.9 KB

    const int bh = blockIdx.x;
    const int b = bh / H_HEADS, h = bh - b * H_HEADS;
    const int t = threadIdx.x;
    const int w = t >> 6, lane = t & 63;
    const int l16 = lane & 15, lhi = lane >> 4;
    const size_t rbase = (size_t)b * T_SEQ;
    const int qoff = h * D_HEAD, koff = E_DIM + h * D_HEAD, voff = 2 * E_DIM + h * D_HEAD;
    const float qscale = 0.051031036307982884f * 1.4426950408889634f;  // 384^-0.5 * log2e

    // Q fragments first (global loads overlap the staging below)
    bf16x8 qf[2][2];
#pragma unroll
    for (int mr = 0; mr < 2; mr++)
#pragma unroll
        for (int kk = 0; kk < 2; kk++)
            qf[mr][kk] = *reinterpret_cast<const bf16x8*>(
                qkv + (rbase + w * 32 + mr * 16 + l16) * QKV_LD + qoff + kk * 32 + lhi * 8);

    // stage K rows (256 x 64), 512 threads x 16B x 4
#pragma unroll
    for (int i = 0; i < 4; i++) {
        int idx = i * 512 + t;
        int r = idx >> 3, c = (idx & 7) * 8;
        *reinterpret_cast<uint4*>(&Ks[r][c]) =
            *reinterpret_cast<const uint4*>(qkv + (rbase + r) * QKV_LD + koff + c);
    }
    // stage V transposed: VTs[d][t]
#pragma unroll
    for (int i = 0; i < 4; i++) {
        int idx = i * 512 + t;
        int r = idx >> 3, d0 = (idx & 7) * 8;
        uint4 val = *reinterpret_cast<const uint4*>(qkv + (rbase + r) * QKV_LD + voff + d0);
        const __hip_bfloat16* p8 = reinterpret_cast<const __hip_bfloat16*>(&val);
#pragma unroll
        for (int j = 0; j < 8; j++) VTs[d0 + j][r] = p8[j];
    }
    __syncthreads();

    float mstate[2][4], lstate[2][4];
    f32x4 oacc[2][4] = {};
#pragma unroll
    for (int mr = 0; mr < 2; mr++)
#pragma unroll
        for (int r = 0; r < 4; r++) {
            mstate[mr][r] = -1e30f;
            lstate[mr][r] = 0.f;
        }

    const int njt = (w >> 1) + 1;
    for (int jt = 0; jt < njt; jt++) {
        const bool diag = (jt == (w >> 1));
        f32x4 s[2][4] = {};
#pragma unroll
        for (int kk = 0; kk < 2; kk++) {
            bf16x8 kf[4];
#pragma unroll
            for (int nr = 0; nr < 4; nr++)
                kf[nr] = *reinterpret_cast<const bf16x8*>(
                    &Ks[jt * 64 + nr * 16 + l16][kk * 32 + lhi * 8]);
#pragma unroll
            for (int mr = 0; mr < 2; mr++)
#pragma unroll
                for (int nr = 0; nr < 4; nr++)
                    s[mr][nr] = MFMA_BF16(qf[mr][kk], kf[nr], s[mr][nr]);
        }
#pragma unroll
        for (int mr = 0; mr < 2; mr++) {
#pragma unroll
            for (int r = 0; r < 4; r++) {
                int qrow = w * 32 + mr * 16 + lhi * 4 + r;
                float pv[4];
                float mx = -1e30f;
                if (diag) {
#pragma unroll
                    for (int nr = 0; nr < 4; nr++) {
                        int kcol = jt * 64 + nr * 16 + l16;
                        float val = s[mr][nr][r] * qscale;
                        if (kcol > qrow) val = -1e30f;
                        pv[nr] = val;
                        mx = fmaxf(mx, val);
                    }
                } else {
#pragma unroll
                    for (int nr = 0; nr < 4; nr++) {
                        float val = s[mr][nr][r] * qscale;
                        pv[nr] = val;
                        mx = fmaxf(mx, val);
                    }
                }
#pragma unroll
                for (int off = 1; off < 16; off <<= 1)
                    mx = fmaxf(mx, __shfl_xor(mx, off, 64));
                float mold = mstate[mr][r];
                float mnew = fmaxf(mold, mx);
                float corr = exp2f(mold - mnew);
                float psum = 0.f;
#pragma unroll
                for (int nr = 0; nr < 4; nr++) {
                    float p = exp2f(pv[nr] - mnew);
                    pv[nr] = p;
                    psum += p;
                }
#pragma unroll
                for (int off = 1; off < 16; off <<= 1)
                    psum += __shfl_xor(psum, off, 64);
                lstate[mr][r] = lstate[mr][r] * corr + psum;
                mstate[mr][r] = mnew;
#pragma unroll
                for (int dr = 0; dr < 4; dr++) oacc[mr][dr][r] *= corr;
#pragma unroll
                for (int nr = 0; nr < 4; nr++)
                    Ps[w][mr * 16 + lhi * 4 + r][nr * 16 + l16] = __float2bfloat16(pv[nr]);
            }
        }
#pragma unroll
        for (int kk = 0; kk < 2; kk++) {
            bf16x8 pa[2], vbf[4];
#pragma unroll
            for (int mr = 0; mr < 2; mr++)
                pa[mr] = *reinterpret_cast<const bf16x8*>(
                    &Ps[w][mr * 16 + l16][kk * 32 + lhi * 8]);
#pragma unroll
            for (int dr = 0; dr < 4; dr++)
                vbf[dr] = *reinterpret_cast<const bf16x8*>(
                    &VTs[dr * 16 + l16][jt * 64 + kk * 32 + lhi * 8]);
#pragma unroll
            for (int mr = 0; mr < 2; mr++)
#pragma unroll
                for (int dr = 0; dr < 4; dr++)
                    oacc[mr][dr] = MFMA_BF16(pa[mr], vbf[dr], oacc[mr][dr]);
        }
    }

#pragma unroll
    for (int mr = 0; mr < 2; mr++) {
#pragma unroll
        for (int r = 0; r < 4; r++) {
            float rl = 1.f / lstate[mr][r];
            int row = w * 32 + mr * 16 + lhi * 4 + r;
#pragma unroll
            for (int dr = 0; dr < 4; dr++)
                o[(rbase + row) * E_DIM + h * D_HEAD + dr * 16 + l16] =
                    __float2bfloat16(oacc[mr][dr][r] * rl);
        }
    }
}

// ---------------------------------------------------------------------------
extern "C" void kernel_launch(void* const* d_in, const int* in_sizes, int n_in,
                              void* d_out, int out_size, void* d_ws, size_t ws_size,
                              hipStream_t stream) {
    const float* x      = (const float*)d_in[0];
    const float* wq     = (const float*)d_in[1];
    const float* wk     = (const float*)d_in[2];
    const float* wv     = (const float*)d_in[3];
    const float* w_proj = (const float*)d_in[4];
    const float* b_proj = (const float*)d_in[5];
    const float* w1     = (const float*)d_in[6];
    const float* b1     = (const float*)d_in[7];
    const float* w2     = (const float*)d_in[8];
    const float* b2     = (const float*)d_in[9];
    const float* g1     = (const float*)d_in[10];
    const float* bt1    = (const float*)d_in[11];
    const float* g2     = (const float*)d_in[12];
    const float* bt2    = (const float*)d_in[13];
    float* out = (float*)d_out;

    char* ws = (char*)d_ws;
    size_t off = 0;
    auto alloc = [&](size_t bytes) {
        void* p = ws + off;
        off += (bytes + 255) & ~(size_t)255;
        return p;
    };
    const size_t wElems = E_DIM * E_DIM;
    const size_t fElems = E_DIM * FF_DIM;
    const size_t actElems = (size_t)NROWS * E_DIM;
    __hip_bfloat16* wqkvT = (__hip_bfloat16*)alloc(3 * wElems * 2);  // [1152][384]
    __hip_bfloat16* wpT   = (__hip_bfloat16*)alloc(wElems * 2);
    __hip_bfloat16* w1T   = (__hip_bfloat16*)alloc(fElems * 2);
    __hip_bfloat16* w2T   = (__hip_bfloat16*)alloc(fElems * 2);
    __hip_bfloat16* lnb   = (__hip_bfloat16*)alloc(actElems * 2);      // ln1 / ln2
    __hip_bfloat16* qkv   = (__hip_bfloat16*)alloc(3 * actElems * 2);  // [32768][1152]
    __hip_bfloat16* ab    = (__hip_bfloat16*)alloc(actElems * 2);      // attn out
    __hip_bfloat16* h1    = qkv;  // FFN hidden (96MB) reuses qkv+ab space
    float* x2 = out;

    // 1) all weights -> bf16 transposed, one launch
    tcast_all_kernel<<<6912, 256, 0, stream>>>(wq, wk, wv, w_proj, w1, w2,
                                               wqkvT, wpT, w1T, w2T);

    // 2) ln1
    ln_kernel<<<NROWS / 4, 256, 0, stream>>>(x, g1, bt1, lnb);

    // 3) fused qkv: [32768][1152]
    gemm256_kernel<0><<<(NROWS / 256) * (QKV_LD / 128), 512, 0, stream>>>(
        lnb, wqkvT, nullptr, nullptr, qkv, nullptr, NROWS, QKV_LD, E_DIM);

    // 4) attention
    attn_kernel<<<B_BATCH * H_HEADS, 512, 0, stream>>>(qkv, ab);

    // 5) x2 = x + attn @ w_proj + b_proj  (f32, in d_out)
    gemm256_kernel<1><<<(NROWS / 256) * (E_DIM / 128), 512, 0, stream>>>(
        ab, wpT, b_proj, x, nullptr, x2, NROWS, E_DIM, E_DIM);

    // 6) ln2
    ln_kernel<<<NROWS / 4, 256, 0, stream>>>(x2, g2, bt2, lnb);

    // 7) h1 = relu(ln2 @ w1 + b1)
    gemm256_kernel<2><<<(NROWS / 256) * (FF_DIM / 128), 512, 0, stream>>>(
        lnb, w1T, b1, nullptr, h1, nullptr, NROWS, FF_DIM, E_DIM);

    // 8) out = x2 + h1 @ w2 + b2
    gemm256_kernel<1><<<(NROWS / 256) * (E_DIM / 128), 512, 0, stream>>>(
        h1, w2T, b2, x2, nullptr, out, NROWS, E_DIM, FF_DIM);
}

// Round 6
// 256.043 us; speedup vs baseline: 1.6752x; 1.0631x over previous
//
#include <hip/hip_runtime.h>
#include <hip/hip_bf16.h>

typedef __attribute__((ext_vector_type(8))) short bf16x8;
typedef __attribute__((ext_vector_type(4))) float f32x4;

#define MFMA_BF16(a, b, c) __builtin_amdgcn_mfma_f32_16x16x32_bf16((a), (b), (c), 0, 0, 0)

#define E_DIM 384
#define T_SEQ 256
#define B_BATCH 128
#define H_HEADS 6
#define D_HEAD 64
#define NROWS (B_BATCH * T_SEQ)   // 32768
#define FF_DIM (4 * E_DIM)        // 1536
#define QKV_LD 1152               // 3*E

__device__ __forceinline__ void load_lds16(const __hip_bfloat16* g, __hip_bfloat16* l) {
    __builtin_amdgcn_global_load_lds(
        (const __attribute__((address_space(1))) void*)g,
        (__attribute__((address_space(3))) void*)l, 16, 0, 0);
}

// ---------------------------------------------------------------------------
// All weight transposes + casts in one launch.
// ---------------------------------------------------------------------------
__global__ void tcast_all_kernel(const float* __restrict__ wq, const float* __restrict__ wk,
                                 const float* __restrict__ wv, const float* __restrict__ wp,
                                 const float* __restrict__ w1, const float* __restrict__ w2,
                                 __hip_bfloat16* __restrict__ wqkvT, __hip_bfloat16* __restrict__ wpT,
                                 __hip_bfloat16* __restrict__ w1T, __hip_bfloat16* __restrict__ w2T) {
    const int WE = E_DIM * E_DIM;   // 147456
    const int FE = E_DIM * FF_DIM;  // 589824
    int idx = blockIdx.x * 256 + threadIdx.x;
    if (idx < 3 * WE) {
        int seg = idx / WE, j = idx - seg * WE;
        const float* W = seg == 0 ? wq : (seg == 1 ? wk : wv);
        int k = j / E_DIM, n = j - k * E_DIM;
        wqkvT[(size_t)seg * WE + (size_t)n * E_DIM + k] = __float2bfloat16(W[j]);
    } else if (idx < 4 * WE) {
        int j = idx - 3 * WE;
        int k = j / E_DIM, n = j - k * E_DIM;
        wpT[(size_t)n * E_DIM + k] = __float2bfloat16(wp[j]);
    } else if (idx < 4 * WE + FE) {
        int j = idx - 4 * WE;
        int k = j / FF_DIM, n = j - k * FF_DIM;
        w1T[(size_t)n * E_DIM + k] = __float2bfloat16(w1[j]);
    } else {
        int j = idx - 4 * WE - FE;
        int k = j / E_DIM, n = j - k * E_DIM;
        w2T[(size_t)n * FF_DIM + k] = __float2bfloat16(w2[j]);
    }
}

// ---------------------------------------------------------------------------
// LayerNorm: x[rows][384] f32 -> out[rows][384] bf16.  One wave per row.
// ---------------------------------------------------------------------------
__global__ __launch_bounds__(256) void ln_kernel(const float* __restrict__ x,
                                                 const float* __restrict__ g,
                                                 const float* __restrict__ bta,
                                                 __hip_bfloat16* __restrict__ out) {
    int row = blockIdx.x * 4 + (threadIdx.x >> 6);
    int lane = threadIdx.x & 63;
    const float* xr = x + (size_t)row * E_DIM;
    float vals[6];
    float s = 0.f;
#pragma unroll
    for (int i = 0; i < 6; i++) {
        vals[i] = xr[lane + i * 64];
        s += vals[i];
    }
#pragma unroll
    for (int off = 1; off < 64; off <<= 1) s += __shfl_xor(s, off, 64);
    float mu = s * (1.f / E_DIM);
    float vv = 0.f;
#pragma unroll
    for (int i = 0; i < 6; i++) {
        float d = vals[i] - mu;
        vv += d * d;
    }
#pragma unroll
    for (int off = 1; off < 64; off <<= 1) vv += __shfl_xor(vv, off, 64);
    float rstd = rsqrtf(vv * (1.f / E_DIM) + 1e-5f);
#pragma unroll
    for (int i = 0; i < 6; i++) {
        int c = lane + i * 64;
        out[(size_t)row * E_DIM + c] =
            __float2bfloat16((vals[i] - mu) * rstd * g[c] + bta[c]);
    }
}

// ---------------------------------------------------------------------------
// Pipelined GEMM: C[M][N] = A[M][K] @ BT[N][K]^T, bf16 in, f32 accum.
// BM=256, BN=128, BK=32. 512 threads = 8 waves (4M x 2N), wave tile 64x64.
// Triple-buffered LDS (3 x 24KB = 72KB -> 2 blocks/CU, 4 waves/SIMD),
// counted s_waitcnt vmcnt(3), raw s_barrier 1x/step, T5 setprio.
// Swizzle (BK=32, 64B rows): slot ^= (R&3)^((R>>2)&3) -> balanced banks.
// EPI: 0 = store bf16; 1 = +bias +f32 residual, store f32; 2 = +bias, relu, bf16
// ---------------------------------------------------------------------------
template <int EPI>
__global__ __launch_bounds__(512, 4) void gemm_k32_kernel(
    const __hip_bfloat16* __restrict__ A, const __hip_bfloat16* __restrict__ BT,
    const float* __restrict__ bias, const float* __restrict__ resid,
    __hip_bfloat16* __restrict__ outb, float* __restrict__ outf,
    int M, int N, int K) {
    // per buffer: A 256x32 (8192 elems) then B 128x32 (4096 elems) = 24KB
    __shared__ __hip_bfloat16 lds[3 * 12288];
    const int t = threadIdx.x;
    const int w = t >> 6, lane = t & 63;
    const int l16 = lane & 15, lhi = lane >> 4;
    const int wm = w >> 1, wn = w & 1;

    // XCD-aware chunked swizzle (grids all divisible by 8)
    const int nwg = gridDim.x;
    const int bid = blockIdx.x;
    const int cpx = nwg >> 3;
    const int swz = (bid & 7) * cpx + (bid >> 3);
    const int nb = N >> 7;
    const int m0 = (swz / nb) * 256;
    const int n0 = (swz % nb) * 128;

    // ---- staging: 3 chunks of 4096 elems (512 thr x 16B) per K-step ----
    const int srow = t >> 2;                                   // 0..127
    const int sslot = t & 3;                                   // 16B slot in 64B row
    const int scol = ((sslot ^ (srow & 3) ^ ((srow >> 2) & 3)) << 3);  // pre-swizzled
    const __hip_bfloat16* pa0 = A + (size_t)(m0 + srow) * K + scol;
    const __hip_bfloat16* pa1 = A + (size_t)(m0 + 128 + srow) * K + scol;
    const __hip_bfloat16* pb0 = BT + (size_t)(n0 + srow) * K + scol;
    const int dstA = t * 8;

    // ---- swizzled ds_read offsets (elems) ----
    int aoff[4], boff[4];
#pragma unroll
    for (int mr = 0; mr < 4; mr++) {
        int R = wm * 64 + mr * 16 + l16;
        int slot = lhi ^ (R & 3) ^ ((R >> 2) & 3);
        aoff[mr] = R * 32 + slot * 8;
    }
#pragma unroll
    for (int nr = 0; nr < 4; nr++) {
        int R = wn * 64 + nr * 16 + l16;
        int slot = lhi ^ (R & 3) ^ ((R >> 2) & 3);
        boff[nr] = 8192 + R * 32 + slot * 8;
    }

    f32x4 acc[4][4] = {};
    const int nk = K >> 5;

#define STAGE(sbuf)                                                           \
    {                                                                         \
        __hip_bfloat16* sbase = &lds[(sbuf) * 12288];                         \
        load_lds16(pa0, sbase + dstA);                                        \
        load_lds16(pa1, sbase + 4096 + dstA);                                 \
        load_lds16(pb0, sbase + 8192 + dstA);                                 \
        pa0 += 32;                                                            \
        pa1 += 32;                                                            \
        pb0 += 32;                                                            \
    }

    // prologue: steps 0,1 -> bufs 0,1
    STAGE(0);
    STAGE(1);
    int rb = 0, sb = 2;

    for (int kt = 0; kt < nk; kt++) {
        if (kt + 1 < nk) {
            asm volatile("s_waitcnt vmcnt(3)" ::: "memory");
        } else {
            asm volatile("s_waitcnt vmcnt(0)" ::: "memory");
        }
        __builtin_amdgcn_s_barrier();
        __builtin_amdgcn_sched_barrier(0);
        if (kt + 2 < nk) STAGE(sb);
        const __hip_bfloat16* base = &lds[rb * 12288];
        bf16x8 af[4], bg[4];
#pragma unroll
        for (int mr = 0; mr < 4; mr++)
            af[mr] = *reinterpret_cast<const bf16x8*>(base + aoff[mr]);
#pragma unroll
        for (int nr = 0; nr < 4; nr++)
            bg[nr] = *reinterpret_cast<const bf16x8*>(base + boff[nr]);
        __builtin_amdgcn_s_setprio(1);
#pragma unroll
        for (int mr = 0; mr < 4; mr++)
#pragma unroll
            for (int nr = 0; nr < 4; nr++)
                acc[mr][nr] = MFMA_BF16(af[mr], bg[nr], acc[mr][nr]);
        __builtin_amdgcn_s_setprio(0);
        rb = rb == 2 ? 0 : rb + 1;
        sb = sb == 2 ? 0 : sb + 1;
    }
#undef STAGE

#pragma unroll
    for (int mr = 0; mr < 4; mr++) {
#pragma unroll
        for (int nr = 0; nr < 4; nr++) {
            int col = n0 + wn * 64 + nr * 16 + l16;
#pragma unroll
            for (int r = 0; r < 4; r++) {
                int row = m0 + wm * 64 + mr * 16 + lhi * 4 + r;
                size_t off = (size_t)row * N + col;
                float v = acc[mr][nr][r];
                if (EPI == 0) {
                    outb[off] = __float2bfloat16(v);
                } else if (EPI == 1) {
                    outf[off] = v + bias[col] + resid[off];
                } else {
                    v += bias[col];
                    outb[off] = __float2bfloat16(v > 0.f ? v : 0.f);
                }
            }
        }
    }
}

// ---------------------------------------------------------------------------
// Causal attention, one block per (b,h). qkv packed [rows][1152].
// 8 waves (512 thr); wave w owns Q rows 32w..32w+31, iterates jt=0..(w>>1).
// exp2-domain online softmax; diagonal-tile-only masking.
// ---------------------------------------------------------------------------
__global__ __launch_bounds__(512, 1) void attn_kernel(
    const __hip_bfloat16* __restrict__ qkv, __hip_bfloat16* __restrict__ o) {
    __shared__ __hip_bfloat16 Ks[T_SEQ][72];     // 36.9 KB
    __shared__ __hip_bfloat16 VTs[D_HEAD][264];  // 33.8 KB
    __shared__ __hip_bfloat16 Ps[8][32][72];     // 36.9 KB

    const int bh = blockIdx.x;
    const int b = bh / H_HEADS, h = bh - b * H_HEADS;
    const int t = threadIdx.x;
    const int w = t >> 6, lane = t & 63;
    const int l16 = lane & 15, lhi = lane >> 4;
    const size_t rbase = (size_t)b * T_SEQ;
    const int qoff = h * D_HEAD, koff = E_DIM + h * D_HEAD, voff = 2 * E_DIM + h * D_HEAD;
    const float qscale = 0.051031036307982884f * 1.4426950408889634f;  // 384^-0.5 * log2e

    // Q fragments first (global loads overlap the staging below)
    bf16x8 qf[2][2];
#pragma unroll
    for (int mr = 0; mr < 2; mr++)
#pragma unroll
        for (int kk = 0; kk < 2; kk++)
            qf[mr][kk] = *reinterpret_cast<const bf16x8*>(
                qkv + (rbase + w * 32 + mr * 16 + l16) * QKV_LD + qoff + kk * 32 + lhi * 8);

    // stage K rows (256 x 64), 512 threads x 16B x 4
#pragma unroll
    for (int i = 0; i < 4; i++) {
        int idx = i * 512 + t;
        int r = idx >> 3, c = (idx & 7) * 8;
        *reinterpret_cast<uint4*>(&Ks[r][c]) =
            *reinterpret_cast<const uint4*>(qkv + (rbase + r) * QKV_LD + koff + c);
    }
    // stage V transposed: VTs[d][t]
#pragma unroll
    for (int i = 0; i < 4; i++) {
        int idx = i * 512 + t;
        int r = idx >> 3, d0 = (idx & 7) * 8;
        uint4 val = *reinterpret_cast<const uint4*>(qkv + (rbase + r) * QKV_LD + voff + d0);
        const __hip_bfloat16* p8 = reinterpret_cast<const __hip_bfloat16*>(&val);
#pragma unroll
        for (int j = 0; j < 8; j++) VTs[d0 + j][r] = p8[j];
    }
    __syncthreads();

    float mstate[2][4], lstate[2][4];
    f32x4 oacc[2][4] = {};
#pragma unroll
    for (int mr = 0; mr < 2; mr++)
#pragma unroll
        for (int r = 0; r < 4; r++) {
            mstate[mr][r] = -1e30f;
            lstate[mr][r] = 0.f;
        }

    const int njt = (w >> 1) + 1;
    for (int jt = 0; jt < njt; jt++) {
        const bool diag = (jt == (w >> 1));
        f32x4 s[2][4] = {};
#pragma unroll
        for (int kk = 0; kk < 2; kk++) {
            bf16x8 kf[4];
#pragma unroll
            for (int nr = 0; nr < 4; nr++)
                kf[nr] = *reinterpret_cast<const bf16x8*>(
                    &Ks[jt * 64 + nr * 16 + l16][kk * 32 + lhi * 8]);
#pragma unroll
            for (int mr = 0; mr < 2; mr++)
#pragma unroll
                for (int nr = 0; nr < 4; nr++)
                    s[mr][nr] = MFMA_BF16(qf[mr][kk], kf[nr], s[mr][nr]);
        }
#pragma unroll
        for (int mr = 0; mr < 2; mr++) {
#pragma unroll
            for (int r = 0; r < 4; r++) {
                int qrow = w * 32 + mr * 16 + lhi * 4 + r;
                float pv[4];
                float mx = -1e30f;
                if (diag) {
#pragma unroll
                    for (int nr = 0; nr < 4; nr++) {
                        int kcol = jt * 64 + nr * 16 + l16;
                        float val = s[mr][nr][r] * qscale;
                        if (kcol > qrow) val = -1e30f;
                        pv[nr] = val;
                        mx = fmaxf(mx, val);
                    }
                } else {
#pragma unroll
                    for (int nr = 0; nr < 4; nr++) {
                        float val = s[mr][nr][r] * qscale;
                        pv[nr] = val;
                        mx = fmaxf(mx, val);
                    }
                }
#pragma unroll
                for (int off = 1; off < 16; off <<= 1)
                    mx = fmaxf(mx, __shfl_xor(mx, off, 64));
                float mold = mstate[mr][r];
                float mnew = fmaxf(mold, mx);
                float corr = exp2f(mold - mnew);
                float psum = 0.f;
#pragma unroll
                for (int nr = 0; nr < 4; nr++) {
                    float p = exp2f(pv[nr] - mnew);
                    pv[nr] = p;
                    psum += p;
                }
#pragma unroll
                for (int off = 1; off < 16; off <<= 1)
                    psum += __shfl_xor(psum, off, 64);
                lstate[mr][r] = lstate[mr][r] * corr + psum;
                mstate[mr][r] = mnew;
#pragma unroll
                for (int dr = 0; dr < 4; dr++) oacc[mr][dr][r] *= corr;
#pragma unroll
                for (int nr = 0; nr < 4; nr++)
                    Ps[w][mr * 16 + lhi * 4 + r][nr * 16 + l16] = __float2bfloat16(pv[nr]);
            }
        }
#pragma unroll
        for (int kk = 0; kk < 2; kk++) {
            bf16x8 pa[2], vbf[4];
#pragma unroll
            for (int mr = 0; mr < 2; mr++)
                pa[mr] = *reinterpret_cast<const bf16x8*>(
                    &Ps[w][mr * 16 + l16][kk * 32 + lhi * 8]);
#pragma unroll
            for (int dr = 0; dr < 4; dr++)
                vbf[dr] = *reinterpret_cast<const bf16x8*>(
                    &VTs[dr * 16 + l16][jt * 64 + kk * 32 + lhi * 8]);
#pragma unroll
            for (int mr = 0; mr < 2; mr++)
#pragma unroll
                for (int dr = 0; dr < 4; dr++)
                    oacc[mr][dr] = MFMA_BF16(pa[mr], vbf[dr], oacc[mr][dr]);
        }
    }

#pragma unroll
    for (int mr = 0; mr < 2; mr++) {
#pragma unroll
        for (int r = 0; r < 4; r++) {
            float rl = 1.f / lstate[mr][r];
            int row = w * 32 + mr * 16 + lhi * 4 + r;
#pragma unroll
            for (int dr = 0; dr < 4; dr++)
                o[(rbase + row) * E_DIM + h * D_HEAD + dr * 16 + l16] =
                    __float2bfloat16(oacc[mr][dr][r] * rl);
        }
    }
}

// ---------------------------------------------------------------------------
extern "C" void kernel_launch(void* const* d_in, const int* in_sizes, int n_in,
                              void* d_out, int out_size, void* d_ws, size_t ws_size,
                              hipStream_t stream) {
    const float* x      = (const float*)d_in[0];
    const float* wq     = (const float*)d_in[1];
    const float* wk     = (const float*)d_in[2];
    const float* wv     = (const float*)d_in[3];
    const float* w_proj = (const float*)d_in[4];
    const float* b_proj = (const float*)d_in[5];
    const float* w1     = (const float*)d_in[6];
    const float* b1     = (const float*)d_in[7];
    const float* w2     = (const float*)d_in[8];
    const float* b2     = (const float*)d_in[9];
    const float* g1     = (const float*)d_in[10];
    const float* bt1    = (const float*)d_in[11];
    const float* g2     = (const float*)d_in[12];
    const float* bt2    = (const float*)d_in[13];
    float* out = (float*)d_out;

    char* ws = (char*)d_ws;
    size_t off = 0;
    auto alloc = [&](size_t bytes) {
        void* p = ws + off;
        off += (bytes + 255) & ~(size_t)255;
        return p;
    };
    const size_t wElems = E_DIM * E_DIM;
    const size_t fElems = E_DIM * FF_DIM;
    const size_t actElems = (size_t)NROWS * E_DIM;
    __hip_bfloat16* wqkvT = (__hip_bfloat16*)alloc(3 * wElems * 2);  // [1152][384]
    __hip_bfloat16* wpT   = (__hip_bfloat16*)alloc(wElems * 2);
    __hip_bfloat16* w1T   = (__hip_bfloat16*)alloc(fElems * 2);
    __hip_bfloat16* w2T   = (__hip_bfloat16*)alloc(fElems * 2);
    __hip_bfloat16* lnb   = (__hip_bfloat16*)alloc(actElems * 2);      // ln1 / ln2
    __hip_bfloat16* qkv   = (__hip_bfloat16*)alloc(3 * actElems * 2);  // [32768][1152]
    __hip_bfloat16* ab    = (__hip_bfloat16*)alloc(actElems * 2);      // attn out
    __hip_bfloat16* h1    = qkv;  // FFN hidden (96MB) reuses qkv+ab space
    float* x2 = out;

    // 1) all weights -> bf16 transposed, one launch
    tcast_all_kernel<<<6912, 256, 0, stream>>>(wq, wk, wv, w_proj, w1, w2,
                                               wqkvT, wpT, w1T, w2T);

    // 2) ln1
    ln_kernel<<<NROWS / 4, 256, 0, stream>>>(x, g1, bt1, lnb);

    // 3) fused qkv: [32768][1152]
    gemm_k32_kernel<0><<<(NROWS / 256) * (QKV_LD / 128), 512, 0, stream>>>(
        lnb, wqkvT, nullptr, nullptr, qkv, nullptr, NROWS, QKV_LD, E_DIM);

    // 4) attention
    attn_kernel<<<B_BATCH * H_HEADS, 512, 0, stream>>>(qkv, ab);

    // 5) x2 = x + attn @ w_proj + b_proj  (f32, in d_out)
    gemm_k32_kernel<1><<<(NROWS / 256) * (E_DIM / 128), 512, 0, stream>>>(
        ab, wpT, b_proj, x, nullptr, x2, NROWS, E_DIM, E_DIM);

    // 6) ln2
    ln_kernel<<<NROWS / 4, 256, 0, stream>>>(x2, g2, bt2, lnb);

    // 7) h1 = relu(ln2 @ w1 + b1)
    gemm_k32_kernel<2><<<(NROWS / 256) * (FF_DIM / 128), 512, 0, stream>>>(
        lnb, w1T, b1, nullptr, h1, nullptr, NROWS, FF_DIM, E_DIM);

    // 8) out = x2 + h1 @ w2 + b2
    gemm_k32_kernel<1><<<(NROWS / 256) * (E_DIM / 128), 512, 0, stream>>>(
        h1, w2T, b2, x2, nullptr, out, NROWS, E_DIM, FF_DIM);
}